// Round 11
// baseline (286.653 us; speedup 1.0000x reference)
//
#include <hip/hip_runtime.h>

#define N_NODES 100000
#define N_EDGES 1600000
#define D_IN 128
#define D_HID 128
#define D_LAT 64

#define BSHIFT 8                          // 256 nodes per bucket
#define NB 392                            // ceil(100352 / 256) buckets
#define CAP 4608                          // slots per bucket region (mean 4082 + 8.2 sigma)
#define EPB 4096                          // edges per partition block
#define PART_BLOCKS ((N_EDGES + EPB - 1) / EPB)   // 391

typedef unsigned short ushort_t;
typedef unsigned int uint_t;
typedef unsigned char uchar_t;
using bf16x8 = __attribute__((ext_vector_type(8))) short;
using f32x4  = __attribute__((ext_vector_type(4))) float;
using f32x2  = __attribute__((ext_vector_type(2))) float;

__device__ inline ushort_t f2bf(float f) {
    uint_t u = __float_as_uint(f);
    return (ushort_t)((u + 0x7fffu + ((u >> 16) & 1u)) >> 16);   // RNE
}
__device__ inline uint_t pack2bf(float a, float b) {
    return (uint_t)f2bf(a) | ((uint_t)f2bf(b) << 16);
}
__device__ inline float bf2f(ushort_t u) {
    return __uint_as_float(((uint_t)u) << 16);
}

// ---------------- fp8 e4m3 helpers (word-select must be compile-time) ----------------
#if __has_builtin(__builtin_amdgcn_cvt_pk_f32_fp8) && __has_builtin(__builtin_amdgcn_cvt_pk_fp8_f32)
#define HW_FP8 1
template<bool HI>
__device__ inline f32x2 fp8pk2f(uint_t v) {
    return __builtin_amdgcn_cvt_pk_f32_fp8(v, HI);       // HI is an ICE here
}
__device__ inline uint_t f2fp8pk4(float a, float b, float c, float d) {
    uint_t w = __builtin_amdgcn_cvt_pk_fp8_f32(a, b, 0, false);
    w = __builtin_amdgcn_cvt_pk_fp8_f32(c, d, w, true);
    return w;
}
__device__ inline uchar_t f2fp8_byte(float f) {
    return (uchar_t)(__builtin_amdgcn_cvt_pk_fp8_f32(f, f, 0, false) & 0xff);
}
#else
// fallback: software e4m3fn (normals exact w/ RNE; subnormals flushed)
__device__ inline float fp8b2f(uint_t b) {
    uint_t em = b & 0x7f;
    if (em == 0) return 0.f;
    uint_t bits = ((em << 20) + (120u << 23)) | ((b & 0x80u) << 24);
    return __uint_as_float(bits);
}
template<bool HI>
__device__ inline f32x2 fp8pk2f(uint_t v) {
    uint_t w = HI ? (v >> 16) : v;
    f32x2 r; r.x = fp8b2f(w & 0xff); r.y = fp8b2f((w >> 8) & 0xff);
    return r;
}
__device__ inline uint_t f2fp8_1(float f) {
    uint_t u = __float_as_uint(f);
    uint_t s = (u >> 31) << 7;
    uint_t au = u & 0x7fffffff;
    if (au >= 0x43e00000u) return s | 0x7e;              // clamp to 448
    if (au < 0x3c000000u) return s;                      // < 2^-7 -> 0 (approx)
    uint_t r = au + 0x0007ffffu + ((au >> 20) & 1u);     // RNE at 3 mantissa bits
    return s | (((r >> 20) - (120u << 3)) & 0x7f);
}
__device__ inline uint_t f2fp8pk4(float a, float b, float c, float d) {
    return f2fp8_1(a) | (f2fp8_1(b) << 8) | (f2fp8_1(c) << 16) | (f2fp8_1(d) << 24);
}
__device__ inline uchar_t f2fp8_byte(float f) { return (uchar_t)f2fp8_1(f); }
#endif

__device__ inline void accf8x4(float* a, uint_t w, int base) {
    f32x2 p0 = fp8pk2f<false>(w);
    f32x2 p1 = fp8pk2f<true>(w);
    a[base + 0] += p0.x; a[base + 1] += p0.y;
    a[base + 2] += p1.x; a[base + 3] += p1.y;
}
__device__ inline void accf8x16(float* a, uint4 u) {
    accf8x4(a, u.x, 0); accf8x4(a, u.y, 4); accf8x4(a, u.z, 8); accf8x4(a, u.w, 12);
}

// ---------------- CSR build: fixed-stride bucketed counting sort ----------------
__global__ void init_cursor_kernel(int* __restrict__ gCur) {
    int t = blockIdx.x * blockDim.x + threadIdx.x;
    if (t < NB) gCur[t] = t * CAP;
}

__global__ __launch_bounds__(256) void bucket_scatter_kernel(const int* __restrict__ src,
                                                             const int* __restrict__ dst,
                                                             int* __restrict__ gCur,
                                                             int* __restrict__ bedges) {
    __shared__ int h[NB];
    __shared__ int start[NB];
    for (int j = threadIdx.x; j < NB; j += 256) h[j] = 0;
    __syncthreads();
    long base = (long)blockIdx.x * EPB + threadIdx.x * 16;   // 16 consecutive edges/thread
    int dc[16], sc[16];
    int cnt = 0;
    if (base + 16 <= N_EDGES) {
        #pragma unroll
        for (int j = 0; j < 4; ++j) {
            int4 d4 = *(const int4*)(dst + base + j * 4);
            int4 s4 = *(const int4*)(src + base + j * 4);
            dc[j * 4 + 0] = d4.x; dc[j * 4 + 1] = d4.y; dc[j * 4 + 2] = d4.z; dc[j * 4 + 3] = d4.w;
            sc[j * 4 + 0] = s4.x; sc[j * 4 + 1] = s4.y; sc[j * 4 + 2] = s4.z; sc[j * 4 + 3] = s4.w;
        }
        cnt = 16;
    } else if (base < N_EDGES) {
        cnt = (int)(N_EDGES - base);
        for (int j = 0; j < cnt; ++j) { dc[j] = dst[base + j]; sc[j] = src[base + j]; }
    }
    for (int j = 0; j < cnt; ++j) atomicAdd(&h[dc[j] >> BSHIFT], 1);
    __syncthreads();
    for (int j = threadIdx.x; j < NB; j += 256)
        start[j] = h[j] ? atomicAdd(&gCur[j], h[j]) : 0;
    __syncthreads();
    for (int j = 0; j < cnt; ++j) {
        int b = dc[j] >> BSHIFT;
        int p = atomicAdd(&start[b], 1);
        if (p < (b + 1) * CAP)                     // overflow clamp (P ~ 1e-16)
            bedges[p] = ((dc[j] & 255) << 24) | sc[j];
    }
}

__global__ __launch_bounds__(256) void bucket_sort_kernel(const int* __restrict__ gCur,
                                                          const int* __restrict__ bedges,
                                                          int* __restrict__ csr,
                                                          int2* __restrict__ off2) {
    __shared__ int sdata[256];
    __shared__ int cur[256];
    int b = blockIdx.x, t = threadIdx.x;
    int r0 = b * CAP;
    int n = gCur[b] - r0;
    if (n > CAP) n = CAP;
    cur[t] = 0;
    __syncthreads();
    for (int k = t; k < n; k += 256) atomicAdd(&cur[(unsigned)bedges[r0 + k] >> 24], 1);
    __syncthreads();
    int c = cur[t];
    sdata[t] = c;
    __syncthreads();
    for (int d = 1; d < 256; d <<= 1) {
        int u = (t >= d) ? sdata[t - d] : 0;
        __syncthreads();
        sdata[t] += u;
        __syncthreads();
    }
    int ex = (t == 0) ? 0 : sdata[t - 1];
    off2[(b << BSHIFT) + t] = make_int2(r0 + ex, c);
    cur[t] = ex;
    __syncthreads();
    for (int k = t; k < n; k += 256) {
        int v = bedges[r0 + k];
        int p = atomicAdd(&cur[(unsigned)v >> 24], 1);
        csr[r0 + p] = v & 0xFFFFFF;
    }
}

// ---------------- fp32 -> (bf16 + fp8) single-pass convert, 16 elems/thread ----------------
__global__ void cvt_both_kernel(const float* __restrict__ in, ushort_t* __restrict__ outb,
                                uchar_t* __restrict__ out8, long n) {
    long i = ((long)blockIdx.x * blockDim.x + threadIdx.x) * 16;
    if (i >= n) return;
    float4 a = *(const float4*)(in + i);
    float4 b = *(const float4*)(in + i + 4);
    float4 c = *(const float4*)(in + i + 8);
    float4 d = *(const float4*)(in + i + 12);
    uint4 ob0, ob1;
    ob0.x = pack2bf(a.x, a.y); ob0.y = pack2bf(a.z, a.w);
    ob0.z = pack2bf(b.x, b.y); ob0.w = pack2bf(b.z, b.w);
    ob1.x = pack2bf(c.x, c.y); ob1.y = pack2bf(c.z, c.w);
    ob1.z = pack2bf(d.x, d.y); ob1.w = pack2bf(d.z, d.w);
    *(uint4*)(outb + i) = ob0;
    *(uint4*)(outb + i + 8) = ob1;
    uint4 o8;
    o8.x = f2fp8pk4(a.x, a.y, a.z, a.w);
    o8.y = f2fp8pk4(b.x, b.y, b.z, b.w);
    o8.z = f2fp8pk4(c.x, c.y, c.z, c.w);
    o8.w = f2fp8pk4(d.x, d.y, d.z, d.w);
    *(uint4*)(out8 + i) = o8;
}

// ---------------- pack [Wl;Wr] (K=256 x N) into MFMA B-fragment order ----------------
__global__ void pack_w_kernel(const float* __restrict__ Wl, const float* __restrict__ Wr,
                              ushort_t* __restrict__ pack, int N) {
    int tid = blockIdx.x * blockDim.x + threadIdx.x;
    int total = (N / 16) * 8 * 64;
    if (tid >= total) return;
    int lane = tid & 63;
    int t = tid >> 6;
    int kt = t & 7;
    int nt = t >> 3;
    int n = nt * 16 + (lane & 15);
    int kbase = kt * 32 + (lane >> 4) * 8;
    ushort_t v[8];
    #pragma unroll
    for (int j = 0; j < 8; ++j) {
        int k = kbase + j;
        float w = (k < 128) ? Wl[k * N + n] : Wr[(k - 128) * N + n];
        v[j] = f2bf(w);
    }
    *(uint4*)(pack + (long)tid * 8) = *(uint4*)v;
}

__global__ void pack_wk128_kernel(const float* __restrict__ W, ushort_t* __restrict__ pack, int N) {
    int tid = blockIdx.x * blockDim.x + threadIdx.x;
    int total = (N / 16) * 4 * 64;
    if (tid >= total) return;
    int lane = tid & 63;
    int t = tid >> 6;
    int kt = t & 3;
    int nt = t >> 2;
    int n = nt * 16 + (lane & 15);
    int kbase = kt * 32 + (lane >> 4) * 8;
    ushort_t v[8];
    #pragma unroll
    for (int j = 0; j < 8; ++j) v[j] = f2bf(W[(kbase + j) * N + n]);
    *(uint4*)(pack + (long)tid * 8) = *(uint4*)v;
}

// ---------------- gather-mean 128-dim fp8, 8-edge pipeline ----------------
// 8 lanes per node (16 dims / 16 B each), 32 nodes per 256-thread block.
__global__ __launch_bounds__(256) void gather_mean_fp8_kernel(
        const int2* __restrict__ off2, const int* __restrict__ csr_src,
        const uchar_t* __restrict__ x8, ushort_t* __restrict__ mean_out) {
    int lane  = threadIdx.x & 7;
    int local = threadIdx.x >> 3;
    long i = (long)blockIdx.x * 32 + local;
    if (i >= N_NODES) return;
    int2 bd = off2[i];
    int beg = bd.x, n = bd.y;
    const uchar_t* base = x8 + lane * 16;
    float acc[16];
    #pragma unroll
    for (int j = 0; j < 16; ++j) acc[j] = 0.f;
    int k = 0;
    for (; k + 8 <= n; k += 8) {
        int s[8];
        #pragma unroll
        for (int j = 0; j < 8; ++j) s[j] = csr_src[beg + k + j];
        uint4 u[8];
        #pragma unroll
        for (int j = 0; j < 8; ++j) u[j] = *(const uint4*)(base + (long)s[j] * 128);
        #pragma unroll
        for (int j = 0; j < 8; ++j) accf8x16(acc, u[j]);
    }
    for (; k < n; ++k) {
        int s0 = csr_src[beg + k];
        uint4 u0 = *(const uint4*)(base + (long)s0 * 128);
        accf8x16(acc, u0);
    }
    float inv = (n > 0) ? 1.f / (float)n : 0.f;
    uint4 o0, o1;
    o0.x = pack2bf(acc[0] * inv,  acc[1] * inv);
    o0.y = pack2bf(acc[2] * inv,  acc[3] * inv);
    o0.z = pack2bf(acc[4] * inv,  acc[5] * inv);
    o0.w = pack2bf(acc[6] * inv,  acc[7] * inv);
    o1.x = pack2bf(acc[8] * inv,  acc[9] * inv);
    o1.y = pack2bf(acc[10] * inv, acc[11] * inv);
    o1.z = pack2bf(acc[12] * inv, acc[13] * inv);
    o1.w = pack2bf(acc[14] * inv, acc[15] * inv);
    ushort_t* mp = mean_out + i * 128 + lane * 16;
    *(uint4*)mp = o0;
    *(uint4*)(mp + 8) = o1;
}

// ---------------- gather-mean 64-dim fp8, 8-edge pipeline ----------------
// 4 lanes per node (16 dims / 16 B each), 64 nodes per 256-thread block.
__global__ __launch_bounds__(256) void gather_mean64_fp8_kernel(
        const int2* __restrict__ off2, const int* __restrict__ csr_src,
        const uchar_t* __restrict__ g8, ushort_t* __restrict__ mean_out) {
    int lane  = threadIdx.x & 3;
    int local = threadIdx.x >> 2;
    long i = (long)blockIdx.x * 64 + local;
    if (i >= N_NODES) return;
    int2 bd = off2[i];
    int beg = bd.x, n = bd.y;
    const uchar_t* base = g8 + lane * 16;
    float acc[16];
    #pragma unroll
    for (int j = 0; j < 16; ++j) acc[j] = 0.f;
    int k = 0;
    for (; k + 8 <= n; k += 8) {
        int s[8];
        #pragma unroll
        for (int j = 0; j < 8; ++j) s[j] = csr_src[beg + k + j];
        uint4 u[8];
        #pragma unroll
        for (int j = 0; j < 8; ++j) u[j] = *(const uint4*)(base + (long)s[j] * 64);
        #pragma unroll
        for (int j = 0; j < 8; ++j) accf8x16(acc, u[j]);
    }
    for (; k < n; ++k) {
        int s0 = csr_src[beg + k];
        uint4 u0 = *(const uint4*)(base + (long)s0 * 64);
        accf8x16(acc, u0);
    }
    float inv = (n > 0) ? 1.f / (float)n : 0.f;
    uint4 o0, o1;
    o0.x = pack2bf(acc[0] * inv,  acc[1] * inv);
    o0.y = pack2bf(acc[2] * inv,  acc[3] * inv);
    o0.z = pack2bf(acc[4] * inv,  acc[5] * inv);
    o0.w = pack2bf(acc[6] * inv,  acc[7] * inv);
    o1.x = pack2bf(acc[8] * inv,  acc[9] * inv);
    o1.y = pack2bf(acc[10] * inv, acc[11] * inv);
    o1.z = pack2bf(acc[12] * inv, acc[13] * inv);
    o1.w = pack2bf(acc[14] * inv, acc[15] * inv);
    ushort_t* mp = mean_out + i * 64 + lane * 16;
    *(uint4*)mp = o0;
    *(uint4*)(mp + 8) = o1;
}

// ---------------- MFMA MLP (K=256): h = relu([mean|x]@W1 + b1) ----------------
template<int NOUT, bool OUT_BF16>
__global__ __launch_bounds__(256) void mfma_mlp_kernel(
        const ushort_t* __restrict__ Am, const ushort_t* __restrict__ Ax,
        const ushort_t* __restrict__ pack, const float* __restrict__ bias,
        void* __restrict__ outv) {
    constexpr int NT = NOUT / 16;
    int lane = threadIdx.x & 63;
    int wave = threadIdx.x >> 6;
    long m0 = (long)blockIdx.x * 64 + wave * 16;
    int r = lane & 15;
    int quad = lane >> 4;
    long arow = m0 + r;
    if (arow > N_NODES - 1) arow = N_NODES - 1;

    bf16x8 areg[8];
    #pragma unroll
    for (int kt = 0; kt < 8; ++kt) {
        const ushort_t* s = (kt < 4) ? Am : Ax;
        int k = (kt & 3) * 32 + quad * 8;
        areg[kt] = *(const bf16x8*)(s + arow * 128 + k);
    }

    f32x4 acc[NT];
    #pragma unroll
    for (int nt = 0; nt < NT; ++nt) acc[nt] = (f32x4){0.f, 0.f, 0.f, 0.f};

    #pragma unroll
    for (int nt = 0; nt < NT; ++nt) {
        #pragma unroll
        for (int kt = 0; kt < 8; ++kt) {
            bf16x8 bfrag = *(const bf16x8*)(pack + ((long)(nt * 8 + kt) * 64 + lane) * 8);
            acc[nt] = __builtin_amdgcn_mfma_f32_16x16x32_bf16(areg[kt], bfrag, acc[nt], 0, 0, 0);
        }
    }

    #pragma unroll
    for (int nt = 0; nt < NT; ++nt) {
        int col = nt * 16 + r;
        float bj = bias[col];
        #pragma unroll
        for (int q = 0; q < 4; ++q) {
            long orow = m0 + quad * 4 + q;
            if (orow < N_NODES) {
                float v = fmaxf(acc[nt][q] + bj, 0.f);
                if (OUT_BF16) ((ushort_t*)outv)[orow * NOUT + col] = f2bf(v);
                else          ((float*)outv)[orow * NOUT + col] = v;
            }
        }
    }
}

// ---------------- MFMA GEMM (K=128): out = [relu]( A @ packedW [+ Cpre] [+ b] ) ----------------
// OUTMODE: 0 = f32 row-major, 1 = bf16 row-major, 2 = fp8 row-major
template<int NOUT, int OUTMODE, bool PRELOAD, bool HASBIAS, bool RELU>
__global__ __launch_bounds__(256) void mfma_gemm_k128_kernel(
        const ushort_t* __restrict__ A, const ushort_t* __restrict__ pack,
        const float* __restrict__ bias, const ushort_t* __restrict__ Cpre,
        void* __restrict__ outv) {
    constexpr int NT = NOUT / 16;
    int lane = threadIdx.x & 63;
    int wave = threadIdx.x >> 6;
    long m0 = (long)blockIdx.x * 64 + wave * 16;
    int r = lane & 15;
    int quad = lane >> 4;
    long arow = m0 + r;
    if (arow > N_NODES - 1) arow = N_NODES - 1;

    bf16x8 areg[4];
    #pragma unroll
    for (int kt = 0; kt < 4; ++kt)
        areg[kt] = *(const bf16x8*)(A + arow * 128 + kt * 32 + quad * 8);

    f32x4 acc[NT];
    #pragma unroll
    for (int nt = 0; nt < NT; ++nt) {
        if (PRELOAD) {
            int col = nt * 16 + r;
            #pragma unroll
            for (int q = 0; q < 4; ++q) {
                long row = m0 + quad * 4 + q;
                if (row > N_NODES - 1) row = N_NODES - 1;
                acc[nt][q] = bf2f(Cpre[row * NOUT + col]);
            }
        } else {
            acc[nt] = (f32x4){0.f, 0.f, 0.f, 0.f};
        }
    }

    #pragma unroll
    for (int nt = 0; nt < NT; ++nt) {
        #pragma unroll
        for (int kt = 0; kt < 4; ++kt) {
            bf16x8 bfrag = *(const bf16x8*)(pack + ((long)(nt * 4 + kt) * 64 + lane) * 8);
            acc[nt] = __builtin_amdgcn_mfma_f32_16x16x32_bf16(areg[kt], bfrag, acc[nt], 0, 0, 0);
        }
    }

    #pragma unroll
    for (int nt = 0; nt < NT; ++nt) {
        int col = nt * 16 + r;
        float bj = HASBIAS ? bias[col] : 0.f;
        #pragma unroll
        for (int q = 0; q < 4; ++q) {
            long orow = m0 + quad * 4 + q;
            if (orow < N_NODES) {
                float v = acc[nt][q] + bj;
                if (RELU) v = fmaxf(v, 0.f);
                if (OUTMODE == 2)      ((uchar_t*)outv)[orow * NOUT + col] = f2fp8_byte(v);
                else if (OUTMODE == 1) ((ushort_t*)outv)[orow * NOUT + col] = f2bf(v);
                else                   ((float*)outv)[orow * NOUT + col] = v;
            }
        }
    }
}

extern "C" void kernel_launch(void* const* d_in, const int* in_sizes, int n_in,
                              void* d_out, int out_size, void* d_ws, size_t ws_size,
                              hipStream_t stream) {
    const float* x    = (const float*)d_in[0];
    const int*   ei   = (const int*)d_in[1];
    const float* W1_l = (const float*)d_in[2];
    const float* W1_r = (const float*)d_in[3];
    const float* b1   = (const float*)d_in[4];
    const float* W2_l = (const float*)d_in[5];
    const float* W2_r = (const float*)d_in[6];
    const float* b2   = (const float*)d_in[7];
    float* out = (float*)d_out;

    const int* src = ei;
    const int* dst = ei + N_EDGES;

    // workspace layout (16B aligned). g8/meang alias mean1; x8 aliases hb
    // (x8 dead before mfma_mlp writes hb; mean1 dead before gemm writes g8).
    int*  gCur   = (int*)d_ws;                        // 512
    int2* off2   = (int2*)(gCur + 512);               // 100608 int2
    int*  bedges = (int*)(off2 + 100608);             // NB*CAP
    int*  csr    = bedges + NB * CAP;                 // NB*CAP
    ushort_t* xb    = (ushort_t*)(csr + NB * CAP);    // 25.6 MB row-major [N][128] bf16
    ushort_t* mean1 = xb + (long)N_NODES * 128;       // 25.6 MB region
    uchar_t*  g8    = (uchar_t*)mean1;                // alias: 6.4 MB fp8 [N][64]
    ushort_t* meang = mean1 + (long)N_NODES * 64;     // alias upper half: bf16 [N][64]
    ushort_t* hb    = mean1 + (long)N_NODES * 128;    // 25.6 MB row-major [N][128] bf16
    uchar_t*  x8    = (uchar_t*)hb;                   // alias: 12.8 MB fp8 [N][128]
    ushort_t* pack1  = hb + (long)N_NODES * 128;      // 256*128 bf16
    ushort_t* pack2l = pack1 + 256 * 128;             // 128*64
    ushort_t* pack2r = pack2l + 128 * 64;             // 128*64

    // ---- CSR build (fixed-stride buckets) ----
    init_cursor_kernel<<<2, 256, 0, stream>>>(gCur);
    bucket_scatter_kernel<<<PART_BLOCKS, 256, 0, stream>>>(src, dst, gCur, bedges);
    bucket_sort_kernel<<<NB, 256, 0, stream>>>(gCur, bedges, csr, off2);

    // ---- precision prep (single pass over x) ----
    cvt_both_kernel<<<((long)N_NODES * 128 / 16 + 255) / 256, 256, 0, stream>>>(
        x, xb, x8, (long)N_NODES * 128);
    pack_w_kernel<<<((128 / 16) * 8 * 64 + 255) / 256, 256, 0, stream>>>(W1_l, W1_r, pack1, 128);
    pack_wk128_kernel<<<((64 / 16) * 4 * 64 + 255) / 256, 256, 0, stream>>>(W2_l, pack2l, 64);
    pack_wk128_kernel<<<((64 / 16) * 4 * 64 + 255) / 256, 256, 0, stream>>>(W2_r, pack2r, 64);

    // ---- layer 1: mean1 = gather(x_fp8); h = relu([mean1|x]@W1 + b1) ----
    gather_mean_fp8_kernel<<<(N_NODES + 31) / 32, 256, 0, stream>>>(off2, csr, x8, mean1);
    mfma_mlp_kernel<128, true><<<(N_NODES + 63) / 64, 256, 0, stream>>>(mean1, xb, pack1, b1, hb);

    // ---- layer 2: g8 = fp8(h@W2_l); meang = gather(g8); out = relu(meang + h@W2_r + b2) ----
    mfma_gemm_k128_kernel<64, 2, false, false, false><<<(N_NODES + 63) / 64, 256, 0, stream>>>(
        hb, pack2l, nullptr, nullptr, g8);
    gather_mean64_fp8_kernel<<<(N_NODES + 63) / 64, 256, 0, stream>>>(off2, csr, g8, meang);
    mfma_gemm_k128_kernel<64, 0, true, true, true><<<(N_NODES + 63) / 64, 256, 0, stream>>>(
        hb, pack2r, b2, meang, out);
}

// Round 12
// 271.997 us; speedup vs baseline: 1.0539x; 1.0539x over previous
//
#include <hip/hip_runtime.h>

#define N_NODES 100000
#define N_EDGES 1600000
#define D_IN 128
#define D_HID 128
#define D_LAT 64

#define BSHIFT 8                          // 256 nodes per bucket
#define NB 392                            // ceil(100352 / 256) buckets
#define CAP 4608                          // slots per bucket region (mean 4082 + 8.2 sigma)
#define EPB 4096                          // edges per partition block
#define PART_BLOCKS ((N_EDGES + EPB - 1) / EPB)   // 391

typedef unsigned short ushort_t;
typedef unsigned int uint_t;
typedef unsigned char uchar_t;
using bf16x8 = __attribute__((ext_vector_type(8))) short;
using f32x4  = __attribute__((ext_vector_type(4))) float;
using f32x2  = __attribute__((ext_vector_type(2))) float;

__device__ inline ushort_t f2bf(float f) {
    uint_t u = __float_as_uint(f);
    return (ushort_t)((u + 0x7fffu + ((u >> 16) & 1u)) >> 16);   // RNE
}
__device__ inline uint_t pack2bf(float a, float b) {
    return (uint_t)f2bf(a) | ((uint_t)f2bf(b) << 16);
}
__device__ inline float bf2f(ushort_t u) {
    return __uint_as_float(((uint_t)u) << 16);
}

// ---------------- fp8 e4m3 helpers (word-select must be compile-time) ----------------
#if __has_builtin(__builtin_amdgcn_cvt_pk_f32_fp8) && __has_builtin(__builtin_amdgcn_cvt_pk_fp8_f32)
#define HW_FP8 1
template<bool HI>
__device__ inline f32x2 fp8pk2f(uint_t v) {
    return __builtin_amdgcn_cvt_pk_f32_fp8(v, HI);       // HI is an ICE here
}
__device__ inline uint_t f2fp8pk4(float a, float b, float c, float d) {
    uint_t w = __builtin_amdgcn_cvt_pk_fp8_f32(a, b, 0, false);
    w = __builtin_amdgcn_cvt_pk_fp8_f32(c, d, w, true);
    return w;
}
__device__ inline uchar_t f2fp8_byte(float f) {
    return (uchar_t)(__builtin_amdgcn_cvt_pk_fp8_f32(f, f, 0, false) & 0xff);
}
#else
// fallback: software e4m3fn (normals exact w/ RNE; subnormals flushed)
__device__ inline float fp8b2f(uint_t b) {
    uint_t em = b & 0x7f;
    if (em == 0) return 0.f;
    uint_t bits = ((em << 20) + (120u << 23)) | ((b & 0x80u) << 24);
    return __uint_as_float(bits);
}
template<bool HI>
__device__ inline f32x2 fp8pk2f(uint_t v) {
    uint_t w = HI ? (v >> 16) : v;
    f32x2 r; r.x = fp8b2f(w & 0xff); r.y = fp8b2f((w >> 8) & 0xff);
    return r;
}
__device__ inline uint_t f2fp8_1(float f) {
    uint_t u = __float_as_uint(f);
    uint_t s = (u >> 31) << 7;
    uint_t au = u & 0x7fffffff;
    if (au >= 0x43e00000u) return s | 0x7e;              // clamp to 448
    if (au < 0x3c000000u) return s;                      // < 2^-7 -> 0 (approx)
    uint_t r = au + 0x0007ffffu + ((au >> 20) & 1u);     // RNE at 3 mantissa bits
    return s | (((r >> 20) - (120u << 3)) & 0x7f);
}
__device__ inline uint_t f2fp8pk4(float a, float b, float c, float d) {
    return f2fp8_1(a) | (f2fp8_1(b) << 8) | (f2fp8_1(c) << 16) | (f2fp8_1(d) << 24);
}
__device__ inline uchar_t f2fp8_byte(float f) { return (uchar_t)f2fp8_1(f); }
#endif

__device__ inline void accf8x4(float* a, uint_t w, int base) {
    f32x2 p0 = fp8pk2f<false>(w);
    f32x2 p1 = fp8pk2f<true>(w);
    a[base + 0] += p0.x; a[base + 1] += p0.y;
    a[base + 2] += p1.x; a[base + 3] += p1.y;
}
__device__ inline void accf8x16(float* a, uint4 u) {
    accf8x4(a, u.x, 0); accf8x4(a, u.y, 4); accf8x4(a, u.z, 8); accf8x4(a, u.w, 12);
}

// ---------------- CSR build: fixed-stride bucketed counting sort ----------------
__global__ void init_cursor_kernel(int* __restrict__ gCur) {
    int t = blockIdx.x * blockDim.x + threadIdx.x;
    if (t < NB) gCur[t] = t * CAP;
}

__global__ __launch_bounds__(256) void bucket_scatter_kernel(const int* __restrict__ src,
                                                             const int* __restrict__ dst,
                                                             int* __restrict__ gCur,
                                                             int* __restrict__ bedges) {
    __shared__ int h[NB];
    __shared__ int start[NB];
    for (int j = threadIdx.x; j < NB; j += 256) h[j] = 0;
    __syncthreads();
    long base = (long)blockIdx.x * EPB + threadIdx.x * 16;   // 16 consecutive edges/thread
    int dc[16], sc[16];
    int cnt = 0;
    if (base + 16 <= N_EDGES) {
        #pragma unroll
        for (int j = 0; j < 4; ++j) {
            int4 d4 = *(const int4*)(dst + base + j * 4);
            int4 s4 = *(const int4*)(src + base + j * 4);
            dc[j * 4 + 0] = d4.x; dc[j * 4 + 1] = d4.y; dc[j * 4 + 2] = d4.z; dc[j * 4 + 3] = d4.w;
            sc[j * 4 + 0] = s4.x; sc[j * 4 + 1] = s4.y; sc[j * 4 + 2] = s4.z; sc[j * 4 + 3] = s4.w;
        }
        cnt = 16;
    } else if (base < N_EDGES) {
        cnt = (int)(N_EDGES - base);
        for (int j = 0; j < cnt; ++j) { dc[j] = dst[base + j]; sc[j] = src[base + j]; }
    }
    for (int j = 0; j < cnt; ++j) atomicAdd(&h[dc[j] >> BSHIFT], 1);
    __syncthreads();
    for (int j = threadIdx.x; j < NB; j += 256)
        start[j] = h[j] ? atomicAdd(&gCur[j], h[j]) : 0;
    __syncthreads();
    for (int j = 0; j < cnt; ++j) {
        int b = dc[j] >> BSHIFT;
        int p = atomicAdd(&start[b], 1);
        if (p < (b + 1) * CAP)                     // overflow clamp (P ~ 1e-16)
            bedges[p] = ((dc[j] & 255) << 24) | sc[j];
    }
}

__global__ __launch_bounds__(256) void bucket_sort_kernel(const int* __restrict__ gCur,
                                                          const int* __restrict__ bedges,
                                                          int* __restrict__ csr,
                                                          int2* __restrict__ off2) {
    __shared__ int sdata[256];
    __shared__ int cur[256];
    int b = blockIdx.x, t = threadIdx.x;
    int r0 = b * CAP;
    int n = gCur[b] - r0;
    if (n > CAP) n = CAP;
    cur[t] = 0;
    __syncthreads();
    for (int k = t; k < n; k += 256) atomicAdd(&cur[(unsigned)bedges[r0 + k] >> 24], 1);
    __syncthreads();
    int c = cur[t];
    sdata[t] = c;
    __syncthreads();
    for (int d = 1; d < 256; d <<= 1) {
        int u = (t >= d) ? sdata[t - d] : 0;
        __syncthreads();
        sdata[t] += u;
        __syncthreads();
    }
    int ex = (t == 0) ? 0 : sdata[t - 1];
    off2[(b << BSHIFT) + t] = make_int2(r0 + ex, c);
    cur[t] = ex;
    __syncthreads();
    for (int k = t; k < n; k += 256) {
        int v = bedges[r0 + k];
        int p = atomicAdd(&cur[(unsigned)v >> 24], 1);
        csr[r0 + p] = v & 0xFFFFFF;
    }
}

// ---------------- fp32 -> (bf16 + fp8) single-pass convert, 16 elems/thread ----------------
__global__ void cvt_both_kernel(const float* __restrict__ in, ushort_t* __restrict__ outb,
                                uchar_t* __restrict__ out8, long n) {
    long i = ((long)blockIdx.x * blockDim.x + threadIdx.x) * 16;
    if (i >= n) return;
    float4 a = *(const float4*)(in + i);
    float4 b = *(const float4*)(in + i + 4);
    float4 c = *(const float4*)(in + i + 8);
    float4 d = *(const float4*)(in + i + 12);
    uint4 ob0, ob1;
    ob0.x = pack2bf(a.x, a.y); ob0.y = pack2bf(a.z, a.w);
    ob0.z = pack2bf(b.x, b.y); ob0.w = pack2bf(b.z, b.w);
    ob1.x = pack2bf(c.x, c.y); ob1.y = pack2bf(c.z, c.w);
    ob1.z = pack2bf(d.x, d.y); ob1.w = pack2bf(d.z, d.w);
    *(uint4*)(outb + i) = ob0;
    *(uint4*)(outb + i + 8) = ob1;
    uint4 o8;
    o8.x = f2fp8pk4(a.x, a.y, a.z, a.w);
    o8.y = f2fp8pk4(b.x, b.y, b.z, b.w);
    o8.z = f2fp8pk4(c.x, c.y, c.z, c.w);
    o8.w = f2fp8pk4(d.x, d.y, d.z, d.w);
    *(uint4*)(out8 + i) = o8;
}

// ---------------- pack [Wl;Wr] (K=256 x N) into MFMA B-fragment order ----------------
__global__ void pack_w_kernel(const float* __restrict__ Wl, const float* __restrict__ Wr,
                              ushort_t* __restrict__ pack, int N) {
    int tid = blockIdx.x * blockDim.x + threadIdx.x;
    int total = (N / 16) * 8 * 64;
    if (tid >= total) return;
    int lane = tid & 63;
    int t = tid >> 6;
    int kt = t & 7;
    int nt = t >> 3;
    int n = nt * 16 + (lane & 15);
    int kbase = kt * 32 + (lane >> 4) * 8;
    ushort_t v[8];
    #pragma unroll
    for (int j = 0; j < 8; ++j) {
        int k = kbase + j;
        float w = (k < 128) ? Wl[k * N + n] : Wr[(k - 128) * N + n];
        v[j] = f2bf(w);
    }
    *(uint4*)(pack + (long)tid * 8) = *(uint4*)v;
}

__global__ void pack_wk128_kernel(const float* __restrict__ W, ushort_t* __restrict__ pack, int N) {
    int tid = blockIdx.x * blockDim.x + threadIdx.x;
    int total = (N / 16) * 4 * 64;
    if (tid >= total) return;
    int lane = tid & 63;
    int t = tid >> 6;
    int kt = t & 3;
    int nt = t >> 2;
    int n = nt * 16 + (lane & 15);
    int kbase = kt * 32 + (lane >> 4) * 8;
    ushort_t v[8];
    #pragma unroll
    for (int j = 0; j < 8; ++j) v[j] = f2bf(W[(kbase + j) * N + n]);
    *(uint4*)(pack + (long)tid * 8) = *(uint4*)v;
}

// ---------------- gather-mean 128-dim fp8, 4-edge pipeline ----------------
// 8 lanes per node (16 dims / 16 B each), 32 nodes per 256-thread block.
__global__ __launch_bounds__(256) void gather_mean_fp8_kernel(
        const int2* __restrict__ off2, const int* __restrict__ csr_src,
        const uchar_t* __restrict__ x8, ushort_t* __restrict__ mean_out) {
    int lane  = threadIdx.x & 7;
    int local = threadIdx.x >> 3;
    long i = (long)blockIdx.x * 32 + local;
    if (i >= N_NODES) return;
    int2 bd = off2[i];
    int beg = bd.x, n = bd.y;
    const uchar_t* base = x8 + lane * 16;
    float acc[16];
    #pragma unroll
    for (int j = 0; j < 16; ++j) acc[j] = 0.f;
    int k = 0;
    for (; k + 4 <= n; k += 4) {
        int s0 = csr_src[beg + k];
        int s1 = csr_src[beg + k + 1];
        int s2 = csr_src[beg + k + 2];
        int s3 = csr_src[beg + k + 3];
        uint4 u0 = *(const uint4*)(base + (long)s0 * 128);
        uint4 u1 = *(const uint4*)(base + (long)s1 * 128);
        uint4 u2 = *(const uint4*)(base + (long)s2 * 128);
        uint4 u3 = *(const uint4*)(base + (long)s3 * 128);
        accf8x16(acc, u0); accf8x16(acc, u1); accf8x16(acc, u2); accf8x16(acc, u3);
    }
    for (; k < n; ++k) {
        int s0 = csr_src[beg + k];
        uint4 u0 = *(const uint4*)(base + (long)s0 * 128);
        accf8x16(acc, u0);
    }
    float inv = (n > 0) ? 1.f / (float)n : 0.f;
    uint4 o0, o1;
    o0.x = pack2bf(acc[0] * inv,  acc[1] * inv);
    o0.y = pack2bf(acc[2] * inv,  acc[3] * inv);
    o0.z = pack2bf(acc[4] * inv,  acc[5] * inv);
    o0.w = pack2bf(acc[6] * inv,  acc[7] * inv);
    o1.x = pack2bf(acc[8] * inv,  acc[9] * inv);
    o1.y = pack2bf(acc[10] * inv, acc[11] * inv);
    o1.z = pack2bf(acc[12] * inv, acc[13] * inv);
    o1.w = pack2bf(acc[14] * inv, acc[15] * inv);
    ushort_t* mp = mean_out + i * 128 + lane * 16;
    *(uint4*)mp = o0;
    *(uint4*)(mp + 8) = o1;
}

// ---------------- gather-mean 64-dim fp8, 4-edge pipeline ----------------
// 4 lanes per node (16 dims / 16 B each), 64 nodes per 256-thread block.
__global__ __launch_bounds__(256) void gather_mean64_fp8_kernel(
        const int2* __restrict__ off2, const int* __restrict__ csr_src,
        const uchar_t* __restrict__ g8, ushort_t* __restrict__ mean_out) {
    int lane  = threadIdx.x & 3;
    int local = threadIdx.x >> 2;
    long i = (long)blockIdx.x * 64 + local;
    if (i >= N_NODES) return;
    int2 bd = off2[i];
    int beg = bd.x, n = bd.y;
    const uchar_t* base = g8 + lane * 16;
    float acc[16];
    #pragma unroll
    for (int j = 0; j < 16; ++j) acc[j] = 0.f;
    int k = 0;
    for (; k + 4 <= n; k += 4) {
        int s0 = csr_src[beg + k];
        int s1 = csr_src[beg + k + 1];
        int s2 = csr_src[beg + k + 2];
        int s3 = csr_src[beg + k + 3];
        uint4 u0 = *(const uint4*)(base + (long)s0 * 64);
        uint4 u1 = *(const uint4*)(base + (long)s1 * 64);
        uint4 u2 = *(const uint4*)(base + (long)s2 * 64);
        uint4 u3 = *(const uint4*)(base + (long)s3 * 64);
        accf8x16(acc, u0); accf8x16(acc, u1); accf8x16(acc, u2); accf8x16(acc, u3);
    }
    for (; k < n; ++k) {
        int s0 = csr_src[beg + k];
        uint4 u0 = *(const uint4*)(base + (long)s0 * 64);
        accf8x16(acc, u0);
    }
    float inv = (n > 0) ? 1.f / (float)n : 0.f;
    uint4 o0, o1;
    o0.x = pack2bf(acc[0] * inv,  acc[1] * inv);
    o0.y = pack2bf(acc[2] * inv,  acc[3] * inv);
    o0.z = pack2bf(acc[4] * inv,  acc[5] * inv);
    o0.w = pack2bf(acc[6] * inv,  acc[7] * inv);
    o1.x = pack2bf(acc[8] * inv,  acc[9] * inv);
    o1.y = pack2bf(acc[10] * inv, acc[11] * inv);
    o1.z = pack2bf(acc[12] * inv, acc[13] * inv);
    o1.w = pack2bf(acc[14] * inv, acc[15] * inv);
    ushort_t* mp = mean_out + i * 64 + lane * 16;
    *(uint4*)mp = o0;
    *(uint4*)(mp + 8) = o1;
}

// ---------------- MFMA MLP (K=256): h = relu([mean|x]@W1 + b1) ----------------
template<int NOUT, bool OUT_BF16>
__global__ __launch_bounds__(256) void mfma_mlp_kernel(
        const ushort_t* __restrict__ Am, const ushort_t* __restrict__ Ax,
        const ushort_t* __restrict__ pack, const float* __restrict__ bias,
        void* __restrict__ outv) {
    constexpr int NT = NOUT / 16;
    int lane = threadIdx.x & 63;
    int wave = threadIdx.x >> 6;
    long m0 = (long)blockIdx.x * 64 + wave * 16;
    int r = lane & 15;
    int quad = lane >> 4;
    long arow = m0 + r;
    if (arow > N_NODES - 1) arow = N_NODES - 1;

    bf16x8 areg[8];
    #pragma unroll
    for (int kt = 0; kt < 8; ++kt) {
        const ushort_t* s = (kt < 4) ? Am : Ax;
        int k = (kt & 3) * 32 + quad * 8;
        areg[kt] = *(const bf16x8*)(s + arow * 128 + k);
    }

    f32x4 acc[NT];
    #pragma unroll
    for (int nt = 0; nt < NT; ++nt) acc[nt] = (f32x4){0.f, 0.f, 0.f, 0.f};

    #pragma unroll
    for (int nt = 0; nt < NT; ++nt) {
        #pragma unroll
        for (int kt = 0; kt < 8; ++kt) {
            bf16x8 bfrag = *(const bf16x8*)(pack + ((long)(nt * 8 + kt) * 64 + lane) * 8);
            acc[nt] = __builtin_amdgcn_mfma_f32_16x16x32_bf16(areg[kt], bfrag, acc[nt], 0, 0, 0);
        }
    }

    #pragma unroll
    for (int nt = 0; nt < NT; ++nt) {
        int col = nt * 16 + r;
        float bj = bias[col];
        #pragma unroll
        for (int q = 0; q < 4; ++q) {
            long orow = m0 + quad * 4 + q;
            if (orow < N_NODES) {
                float v = fmaxf(acc[nt][q] + bj, 0.f);
                if (OUT_BF16) ((ushort_t*)outv)[orow * NOUT + col] = f2bf(v);
                else          ((float*)outv)[orow * NOUT + col] = v;
            }
        }
    }
}

// ---------------- MFMA GEMM (K=128): out = [relu]( A @ packedW [+ Cpre] [+ b] ) ----------------
// OUTMODE: 0 = f32 row-major, 1 = bf16 row-major, 2 = fp8 row-major
template<int NOUT, int OUTMODE, bool PRELOAD, bool HASBIAS, bool RELU>
__global__ __launch_bounds__(256) void mfma_gemm_k128_kernel(
        const ushort_t* __restrict__ A, const ushort_t* __restrict__ pack,
        const float* __restrict__ bias, const ushort_t* __restrict__ Cpre,
        void* __restrict__ outv) {
    constexpr int NT = NOUT / 16;
    int lane = threadIdx.x & 63;
    int wave = threadIdx.x >> 6;
    long m0 = (long)blockIdx.x * 64 + wave * 16;
    int r = lane & 15;
    int quad = lane >> 4;
    long arow = m0 + r;
    if (arow > N_NODES - 1) arow = N_NODES - 1;

    bf16x8 areg[4];
    #pragma unroll
    for (int kt = 0; kt < 4; ++kt)
        areg[kt] = *(const bf16x8*)(A + arow * 128 + kt * 32 + quad * 8);

    f32x4 acc[NT];
    #pragma unroll
    for (int nt = 0; nt < NT; ++nt) {
        if (PRELOAD) {
            int col = nt * 16 + r;
            #pragma unroll
            for (int q = 0; q < 4; ++q) {
                long row = m0 + quad * 4 + q;
                if (row > N_NODES - 1) row = N_NODES - 1;
                acc[nt][q] = bf2f(Cpre[row * NOUT + col]);
            }
        } else {
            acc[nt] = (f32x4){0.f, 0.f, 0.f, 0.f};
        }
    }

    #pragma unroll
    for (int nt = 0; nt < NT; ++nt) {
        #pragma unroll
        for (int kt = 0; kt < 4; ++kt) {
            bf16x8 bfrag = *(const bf16x8*)(pack + ((long)(nt * 4 + kt) * 64 + lane) * 8);
            acc[nt] = __builtin_amdgcn_mfma_f32_16x16x32_bf16(areg[kt], bfrag, acc[nt], 0, 0, 0);
        }
    }

    #pragma unroll
    for (int nt = 0; nt < NT; ++nt) {
        int col = nt * 16 + r;
        float bj = HASBIAS ? bias[col] : 0.f;
        #pragma unroll
        for (int q = 0; q < 4; ++q) {
            long orow = m0 + quad * 4 + q;
            if (orow < N_NODES) {
                float v = acc[nt][q] + bj;
                if (RELU) v = fmaxf(v, 0.f);
                if (OUTMODE == 2)      ((uchar_t*)outv)[orow * NOUT + col] = f2fp8_byte(v);
                else if (OUTMODE == 1) ((ushort_t*)outv)[orow * NOUT + col] = f2bf(v);
                else                   ((float*)outv)[orow * NOUT + col] = v;
            }
        }
    }
}

extern "C" void kernel_launch(void* const* d_in, const int* in_sizes, int n_in,
                              void* d_out, int out_size, void* d_ws, size_t ws_size,
                              hipStream_t stream) {
    const float* x    = (const float*)d_in[0];
    const int*   ei   = (const int*)d_in[1];
    const float* W1_l = (const float*)d_in[2];
    const float* W1_r = (const float*)d_in[3];
    const float* b1   = (const float*)d_in[4];
    const float* W2_l = (const float*)d_in[5];
    const float* W2_r = (const float*)d_in[6];
    const float* b2   = (const float*)d_in[7];
    float* out = (float*)d_out;

    const int* src = ei;
    const int* dst = ei + N_EDGES;

    // workspace layout (16B aligned). g8/meang alias mean1; x8 aliases hb
    // (x8 dead before mfma_mlp writes hb; mean1 dead before gemm writes g8).
    int*  gCur   = (int*)d_ws;                        // 512
    int2* off2   = (int2*)(gCur + 512);               // 100608 int2
    int*  bedges = (int*)(off2 + 100608);             // NB*CAP
    int*  csr    = bedges + NB * CAP;                 // NB*CAP
    ushort_t* xb    = (ushort_t*)(csr + NB * CAP);    // 25.6 MB row-major [N][128] bf16
    ushort_t* mean1 = xb + (long)N_NODES * 128;       // 25.6 MB region
    uchar_t*  g8    = (uchar_t*)mean1;                // alias: 6.4 MB fp8 [N][64]
    ushort_t* meang = mean1 + (long)N_NODES * 64;     // alias upper half: bf16 [N][64]
    ushort_t* hb    = mean1 + (long)N_NODES * 128;    // 25.6 MB row-major [N][128] bf16
    uchar_t*  x8    = (uchar_t*)hb;                   // alias: 12.8 MB fp8 [N][128]
    ushort_t* pack1  = hb + (long)N_NODES * 128;      // 256*128 bf16
    ushort_t* pack2l = pack1 + 256 * 128;             // 128*64
    ushort_t* pack2r = pack2l + 128 * 64;             // 128*64

    // ---- CSR build (fixed-stride buckets) ----
    init_cursor_kernel<<<2, 256, 0, stream>>>(gCur);
    bucket_scatter_kernel<<<PART_BLOCKS, 256, 0, stream>>>(src, dst, gCur, bedges);
    bucket_sort_kernel<<<NB, 256, 0, stream>>>(gCur, bedges, csr, off2);

    // ---- precision prep (single pass over x) ----
    cvt_both_kernel<<<((long)N_NODES * 128 / 16 + 255) / 256, 256, 0, stream>>>(
        x, xb, x8, (long)N_NODES * 128);
    pack_w_kernel<<<((128 / 16) * 8 * 64 + 255) / 256, 256, 0, stream>>>(W1_l, W1_r, pack1, 128);
    pack_wk128_kernel<<<((64 / 16) * 4 * 64 + 255) / 256, 256, 0, stream>>>(W2_l, pack2l, 64);
    pack_wk128_kernel<<<((64 / 16) * 4 * 64 + 255) / 256, 256, 0, stream>>>(W2_r, pack2r, 64);

    // ---- layer 1: mean1 = gather(x_fp8); h = relu([mean1|x]@W1 + b1) ----
    gather_mean_fp8_kernel<<<(N_NODES + 31) / 32, 256, 0, stream>>>(off2, csr, x8, mean1);
    mfma_mlp_kernel<128, true><<<(N_NODES + 63) / 64, 256, 0, stream>>>(mean1, xb, pack1, b1, hb);

    // ---- layer 2: g8 = fp8(h@W2_l); meang = gather(g8); out = relu(meang + h@W2_r + b2) ----
    mfma_gemm_k128_kernel<64, 2, false, false, false><<<(N_NODES + 63) / 64, 256, 0, stream>>>(
        hb, pack2l, nullptr, nullptr, g8);
    gather_mean64_fp8_kernel<<<(N_NODES + 63) / 64, 256, 0, stream>>>(off2, csr, g8, meang);
    mfma_gemm_k128_kernel<64, 0, true, true, true><<<(N_NODES + 63) / 64, 256, 0, stream>>>(
        hb, pack2r, b2, meang, out);
}

// Round 13
// 262.570 us; speedup vs baseline: 1.0917x; 1.0359x over previous
//
#include <hip/hip_runtime.h>

#define N_NODES 100000
#define N_EDGES 1600000
#define D_IN 128
#define D_HID 128
#define D_LAT 64

#define BSHIFT 8                          // 256 nodes per bucket
#define NB 392                            // ceil(100352 / 256) buckets
#define CAP 4608                          // slots per bucket region (mean 4082 + 8.2 sigma)
#define EPB 4096                          // edges per partition block
#define PART_BLOCKS ((N_EDGES + EPB - 1) / EPB)   // 391

typedef unsigned short ushort_t;
typedef unsigned int uint_t;
typedef unsigned char uchar_t;
using bf16x8 = __attribute__((ext_vector_type(8))) short;
using f32x4  = __attribute__((ext_vector_type(4))) float;
using f32x2  = __attribute__((ext_vector_type(2))) float;

__device__ inline ushort_t f2bf(float f) {
    uint_t u = __float_as_uint(f);
    return (ushort_t)((u + 0x7fffu + ((u >> 16) & 1u)) >> 16);   // RNE
}
__device__ inline uint_t pack2bf(float a, float b) {
    return (uint_t)f2bf(a) | ((uint_t)f2bf(b) << 16);
}
__device__ inline float bf2f(ushort_t u) {
    return __uint_as_float(((uint_t)u) << 16);
}

// ---------------- fp8 e4m3 helpers (word-select must be compile-time) ----------------
#if __has_builtin(__builtin_amdgcn_cvt_pk_f32_fp8) && __has_builtin(__builtin_amdgcn_cvt_pk_fp8_f32)
#define HW_FP8 1
template<bool HI>
__device__ inline f32x2 fp8pk2f(uint_t v) {
    return __builtin_amdgcn_cvt_pk_f32_fp8(v, HI);       // HI is an ICE here
}
__device__ inline uint_t f2fp8pk4(float a, float b, float c, float d) {
    uint_t w = __builtin_amdgcn_cvt_pk_fp8_f32(a, b, 0, false);
    w = __builtin_amdgcn_cvt_pk_fp8_f32(c, d, w, true);
    return w;
}
__device__ inline uchar_t f2fp8_byte(float f) {
    return (uchar_t)(__builtin_amdgcn_cvt_pk_fp8_f32(f, f, 0, false) & 0xff);
}
#else
// fallback: software e4m3fn (normals exact w/ RNE; subnormals flushed)
__device__ inline float fp8b2f(uint_t b) {
    uint_t em = b & 0x7f;
    if (em == 0) return 0.f;
    uint_t bits = ((em << 20) + (120u << 23)) | ((b & 0x80u) << 24);
    return __uint_as_float(bits);
}
template<bool HI>
__device__ inline f32x2 fp8pk2f(uint_t v) {
    uint_t w = HI ? (v >> 16) : v;
    f32x2 r; r.x = fp8b2f(w & 0xff); r.y = fp8b2f((w >> 8) & 0xff);
    return r;
}
__device__ inline uint_t f2fp8_1(float f) {
    uint_t u = __float_as_uint(f);
    uint_t s = (u >> 31) << 7;
    uint_t au = u & 0x7fffffff;
    if (au >= 0x43e00000u) return s | 0x7e;              // clamp to 448
    if (au < 0x3c000000u) return s;                      // < 2^-7 -> 0 (approx)
    uint_t r = au + 0x0007ffffu + ((au >> 20) & 1u);     // RNE at 3 mantissa bits
    return s | (((r >> 20) - (120u << 3)) & 0x7f);
}
__device__ inline uint_t f2fp8pk4(float a, float b, float c, float d) {
    return f2fp8_1(a) | (f2fp8_1(b) << 8) | (f2fp8_1(c) << 16) | (f2fp8_1(d) << 24);
}
__device__ inline uchar_t f2fp8_byte(float f) { return (uchar_t)f2fp8_1(f); }
#endif

__device__ inline void accf8x4(float* a, uint_t w, int base) {
    f32x2 p0 = fp8pk2f<false>(w);
    f32x2 p1 = fp8pk2f<true>(w);
    a[base + 0] += p0.x; a[base + 1] += p0.y;
    a[base + 2] += p1.x; a[base + 3] += p1.y;
}
__device__ inline void accf8x16(float* a, uint4 u) {
    accf8x4(a, u.x, 0); accf8x4(a, u.y, 4); accf8x4(a, u.z, 8); accf8x4(a, u.w, 12);
}

// ---------------- fused prep: weight packs + cursor init (one launch) ----------------
// blocks 0..15: pack1 (K=256, N=128); 16..19: pack2l; 20..23: pack2r; 24..25: init gCur
__device__ inline void pack_w256(const float* Wl, const float* Wr, ushort_t* pack,
                                 int N, int tid) {
    int lane = tid & 63;
    int t = tid >> 6;
    int kt = t & 7;
    int nt = t >> 3;
    int n = nt * 16 + (lane & 15);
    int kbase = kt * 32 + (lane >> 4) * 8;
    ushort_t v[8];
    #pragma unroll
    for (int j = 0; j < 8; ++j) {
        int k = kbase + j;
        float w = (k < 128) ? Wl[k * N + n] : Wr[(k - 128) * N + n];
        v[j] = f2bf(w);
    }
    *(uint4*)(pack + (long)tid * 8) = *(uint4*)v;
}
__device__ inline void pack_w128(const float* W, ushort_t* pack, int N, int tid) {
    int lane = tid & 63;
    int t = tid >> 6;
    int kt = t & 3;
    int nt = t >> 2;
    int n = nt * 16 + (lane & 15);
    int kbase = kt * 32 + (lane >> 4) * 8;
    ushort_t v[8];
    #pragma unroll
    for (int j = 0; j < 8; ++j) v[j] = f2bf(W[(kbase + j) * N + n]);
    *(uint4*)(pack + (long)tid * 8) = *(uint4*)v;
}

__global__ __launch_bounds__(256) void prep_kernel(
        const float* __restrict__ W1_l, const float* __restrict__ W1_r,
        ushort_t* __restrict__ pack1,
        const float* __restrict__ W2_l, ushort_t* __restrict__ pack2l,
        const float* __restrict__ W2_r, ushort_t* __restrict__ pack2r,
        int* __restrict__ gCur) {
    int b = blockIdx.x;
    if (b < 16) {
        pack_w256(W1_l, W1_r, pack1, 128, b * 256 + threadIdx.x);
    } else if (b < 20) {
        pack_w128(W2_l, pack2l, 64, (b - 16) * 256 + threadIdx.x);
    } else if (b < 24) {
        pack_w128(W2_r, pack2r, 64, (b - 20) * 256 + threadIdx.x);
    } else {
        int t = (b - 24) * 256 + threadIdx.x;
        if (t < NB) gCur[t] = t * CAP;
    }
}

// ---------------- CSR build: fixed-stride bucketed counting sort ----------------
__global__ __launch_bounds__(256) void bucket_scatter_kernel(const int* __restrict__ src,
                                                             const int* __restrict__ dst,
                                                             int* __restrict__ gCur,
                                                             int* __restrict__ bedges) {
    __shared__ int h[NB];
    __shared__ int start[NB];
    for (int j = threadIdx.x; j < NB; j += 256) h[j] = 0;
    __syncthreads();
    long base = (long)blockIdx.x * EPB + threadIdx.x * 16;   // 16 consecutive edges/thread
    int dc[16], sc[16];
    int cnt = 0;
    if (base + 16 <= N_EDGES) {
        #pragma unroll
        for (int j = 0; j < 4; ++j) {
            int4 d4 = *(const int4*)(dst + base + j * 4);
            int4 s4 = *(const int4*)(src + base + j * 4);
            dc[j * 4 + 0] = d4.x; dc[j * 4 + 1] = d4.y; dc[j * 4 + 2] = d4.z; dc[j * 4 + 3] = d4.w;
            sc[j * 4 + 0] = s4.x; sc[j * 4 + 1] = s4.y; sc[j * 4 + 2] = s4.z; sc[j * 4 + 3] = s4.w;
        }
        cnt = 16;
    } else if (base < N_EDGES) {
        cnt = (int)(N_EDGES - base);
        for (int j = 0; j < cnt; ++j) { dc[j] = dst[base + j]; sc[j] = src[base + j]; }
    }
    for (int j = 0; j < cnt; ++j) atomicAdd(&h[dc[j] >> BSHIFT], 1);
    __syncthreads();
    for (int j = threadIdx.x; j < NB; j += 256)
        start[j] = h[j] ? atomicAdd(&gCur[j], h[j]) : 0;
    __syncthreads();
    for (int j = 0; j < cnt; ++j) {
        int b = dc[j] >> BSHIFT;
        int p = atomicAdd(&start[b], 1);
        if (p < (b + 1) * CAP)                     // overflow clamp (P ~ 1e-16)
            bedges[p] = ((dc[j] & 255) << 24) | sc[j];
    }
}

// per-bucket LDS counting sort; int4 reads (CAP region is 16B-aligned + padded)
__global__ __launch_bounds__(256) void bucket_sort_kernel(const int* __restrict__ gCur,
                                                          const int* __restrict__ bedges,
                                                          int* __restrict__ csr,
                                                          int2* __restrict__ off2) {
    __shared__ int sdata[256];
    __shared__ int cur[256];
    int b = blockIdx.x, t = threadIdx.x;
    int r0 = b * CAP;
    int n = gCur[b] - r0;
    if (n > CAP) n = CAP;
    cur[t] = 0;
    __syncthreads();
    for (int k = t * 4; k < n; k += 1024) {
        int4 v4 = *(const int4*)(bedges + r0 + k);
        int m = n - k;
        atomicAdd(&cur[(unsigned)v4.x >> 24], 1);
        if (m > 1) atomicAdd(&cur[(unsigned)v4.y >> 24], 1);
        if (m > 2) atomicAdd(&cur[(unsigned)v4.z >> 24], 1);
        if (m > 3) atomicAdd(&cur[(unsigned)v4.w >> 24], 1);
    }
    __syncthreads();
    int c = cur[t];
    sdata[t] = c;
    __syncthreads();
    for (int d = 1; d < 256; d <<= 1) {
        int u = (t >= d) ? sdata[t - d] : 0;
        __syncthreads();
        sdata[t] += u;
        __syncthreads();
    }
    int ex = (t == 0) ? 0 : sdata[t - 1];
    off2[(b << BSHIFT) + t] = make_int2(r0 + ex, c);
    cur[t] = ex;
    __syncthreads();
    for (int k = t * 4; k < n; k += 1024) {
        int4 v4 = *(const int4*)(bedges + r0 + k);
        int m = n - k;
        {
            int p = atomicAdd(&cur[(unsigned)v4.x >> 24], 1);
            csr[r0 + p] = v4.x & 0xFFFFFF;
        }
        if (m > 1) {
            int p = atomicAdd(&cur[(unsigned)v4.y >> 24], 1);
            csr[r0 + p] = v4.y & 0xFFFFFF;
        }
        if (m > 2) {
            int p = atomicAdd(&cur[(unsigned)v4.z >> 24], 1);
            csr[r0 + p] = v4.z & 0xFFFFFF;
        }
        if (m > 3) {
            int p = atomicAdd(&cur[(unsigned)v4.w >> 24], 1);
            csr[r0 + p] = v4.w & 0xFFFFFF;
        }
    }
}

// ---------------- fp32 -> (bf16 + fp8) single-pass convert, 16 elems/thread ----------------
__global__ void cvt_both_kernel(const float* __restrict__ in, ushort_t* __restrict__ outb,
                                uchar_t* __restrict__ out8, long n) {
    long i = ((long)blockIdx.x * blockDim.x + threadIdx.x) * 16;
    if (i >= n) return;
    float4 a = *(const float4*)(in + i);
    float4 b = *(const float4*)(in + i + 4);
    float4 c = *(const float4*)(in + i + 8);
    float4 d = *(const float4*)(in + i + 12);
    uint4 ob0, ob1;
    ob0.x = pack2bf(a.x, a.y); ob0.y = pack2bf(a.z, a.w);
    ob0.z = pack2bf(b.x, b.y); ob0.w = pack2bf(b.z, b.w);
    ob1.x = pack2bf(c.x, c.y); ob1.y = pack2bf(c.z, c.w);
    ob1.z = pack2bf(d.x, d.y); ob1.w = pack2bf(d.z, d.w);
    *(uint4*)(outb + i) = ob0;
    *(uint4*)(outb + i + 8) = ob1;
    uint4 o8;
    o8.x = f2fp8pk4(a.x, a.y, a.z, a.w);
    o8.y = f2fp8pk4(b.x, b.y, b.z, b.w);
    o8.z = f2fp8pk4(c.x, c.y, c.z, c.w);
    o8.w = f2fp8pk4(d.x, d.y, d.z, d.w);
    *(uint4*)(out8 + i) = o8;
}

// ---------------- gather-mean 128-dim fp8, 4-edge pipeline ----------------
// 8 lanes per node (16 dims / 16 B each), 32 nodes per 256-thread block.
__global__ __launch_bounds__(256) void gather_mean_fp8_kernel(
        const int2* __restrict__ off2, const int* __restrict__ csr_src,
        const uchar_t* __restrict__ x8, ushort_t* __restrict__ mean_out) {
    int lane  = threadIdx.x & 7;
    int local = threadIdx.x >> 3;
    long i = (long)blockIdx.x * 32 + local;
    if (i >= N_NODES) return;
    int2 bd = off2[i];
    int beg = bd.x, n = bd.y;
    const uchar_t* base = x8 + lane * 16;
    float acc[16];
    #pragma unroll
    for (int j = 0; j < 16; ++j) acc[j] = 0.f;
    int k = 0;
    for (; k + 4 <= n; k += 4) {
        int s0 = csr_src[beg + k];
        int s1 = csr_src[beg + k + 1];
        int s2 = csr_src[beg + k + 2];
        int s3 = csr_src[beg + k + 3];
        uint4 u0 = *(const uint4*)(base + (long)s0 * 128);
        uint4 u1 = *(const uint4*)(base + (long)s1 * 128);
        uint4 u2 = *(const uint4*)(base + (long)s2 * 128);
        uint4 u3 = *(const uint4*)(base + (long)s3 * 128);
        accf8x16(acc, u0); accf8x16(acc, u1); accf8x16(acc, u2); accf8x16(acc, u3);
    }
    for (; k < n; ++k) {
        int s0 = csr_src[beg + k];
        uint4 u0 = *(const uint4*)(base + (long)s0 * 128);
        accf8x16(acc, u0);
    }
    float inv = (n > 0) ? 1.f / (float)n : 0.f;
    uint4 o0, o1;
    o0.x = pack2bf(acc[0] * inv,  acc[1] * inv);
    o0.y = pack2bf(acc[2] * inv,  acc[3] * inv);
    o0.z = pack2bf(acc[4] * inv,  acc[5] * inv);
    o0.w = pack2bf(acc[6] * inv,  acc[7] * inv);
    o1.x = pack2bf(acc[8] * inv,  acc[9] * inv);
    o1.y = pack2bf(acc[10] * inv, acc[11] * inv);
    o1.z = pack2bf(acc[12] * inv, acc[13] * inv);
    o1.w = pack2bf(acc[14] * inv, acc[15] * inv);
    ushort_t* mp = mean_out + i * 128 + lane * 16;
    *(uint4*)mp = o0;
    *(uint4*)(mp + 8) = o1;
}

// ---------------- gather-mean 64-dim fp8, 4-edge pipeline ----------------
// 4 lanes per node (16 dims / 16 B each), 64 nodes per 256-thread block.
__global__ __launch_bounds__(256) void gather_mean64_fp8_kernel(
        const int2* __restrict__ off2, const int* __restrict__ csr_src,
        const uchar_t* __restrict__ g8, ushort_t* __restrict__ mean_out) {
    int lane  = threadIdx.x & 3;
    int local = threadIdx.x >> 2;
    long i = (long)blockIdx.x * 64 + local;
    if (i >= N_NODES) return;
    int2 bd = off2[i];
    int beg = bd.x, n = bd.y;
    const uchar_t* base = g8 + lane * 16;
    float acc[16];
    #pragma unroll
    for (int j = 0; j < 16; ++j) acc[j] = 0.f;
    int k = 0;
    for (; k + 4 <= n; k += 4) {
        int s0 = csr_src[beg + k];
        int s1 = csr_src[beg + k + 1];
        int s2 = csr_src[beg + k + 2];
        int s3 = csr_src[beg + k + 3];
        uint4 u0 = *(const uint4*)(base + (long)s0 * 64);
        uint4 u1 = *(const uint4*)(base + (long)s1 * 64);
        uint4 u2 = *(const uint4*)(base + (long)s2 * 64);
        uint4 u3 = *(const uint4*)(base + (long)s3 * 64);
        accf8x16(acc, u0); accf8x16(acc, u1); accf8x16(acc, u2); accf8x16(acc, u3);
    }
    for (; k < n; ++k) {
        int s0 = csr_src[beg + k];
        uint4 u0 = *(const uint4*)(base + (long)s0 * 64);
        accf8x16(acc, u0);
    }
    float inv = (n > 0) ? 1.f / (float)n : 0.f;
    uint4 o0, o1;
    o0.x = pack2bf(acc[0] * inv,  acc[1] * inv);
    o0.y = pack2bf(acc[2] * inv,  acc[3] * inv);
    o0.z = pack2bf(acc[4] * inv,  acc[5] * inv);
    o0.w = pack2bf(acc[6] * inv,  acc[7] * inv);
    o1.x = pack2bf(acc[8] * inv,  acc[9] * inv);
    o1.y = pack2bf(acc[10] * inv, acc[11] * inv);
    o1.z = pack2bf(acc[12] * inv, acc[13] * inv);
    o1.w = pack2bf(acc[14] * inv, acc[15] * inv);
    ushort_t* mp = mean_out + i * 64 + lane * 16;
    *(uint4*)mp = o0;
    *(uint4*)(mp + 8) = o1;
}

// ---------------- MFMA MLP (K=256): h = relu([mean|x]@W1 + b1) ----------------
template<int NOUT, bool OUT_BF16>
__global__ __launch_bounds__(256) void mfma_mlp_kernel(
        const ushort_t* __restrict__ Am, const ushort_t* __restrict__ Ax,
        const ushort_t* __restrict__ pack, const float* __restrict__ bias,
        void* __restrict__ outv) {
    constexpr int NT = NOUT / 16;
    int lane = threadIdx.x & 63;
    int wave = threadIdx.x >> 6;
    long m0 = (long)blockIdx.x * 64 + wave * 16;
    int r = lane & 15;
    int quad = lane >> 4;
    long arow = m0 + r;
    if (arow > N_NODES - 1) arow = N_NODES - 1;

    bf16x8 areg[8];
    #pragma unroll
    for (int kt = 0; kt < 8; ++kt) {
        const ushort_t* s = (kt < 4) ? Am : Ax;
        int k = (kt & 3) * 32 + quad * 8;
        areg[kt] = *(const bf16x8*)(s + arow * 128 + k);
    }

    f32x4 acc[NT];
    #pragma unroll
    for (int nt = 0; nt < NT; ++nt) acc[nt] = (f32x4){0.f, 0.f, 0.f, 0.f};

    #pragma unroll
    for (int nt = 0; nt < NT; ++nt) {
        #pragma unroll
        for (int kt = 0; kt < 8; ++kt) {
            bf16x8 bfrag = *(const bf16x8*)(pack + ((long)(nt * 8 + kt) * 64 + lane) * 8);
            acc[nt] = __builtin_amdgcn_mfma_f32_16x16x32_bf16(areg[kt], bfrag, acc[nt], 0, 0, 0);
        }
    }

    #pragma unroll
    for (int nt = 0; nt < NT; ++nt) {
        int col = nt * 16 + r;
        float bj = bias[col];
        #pragma unroll
        for (int q = 0; q < 4; ++q) {
            long orow = m0 + quad * 4 + q;
            if (orow < N_NODES) {
                float v = fmaxf(acc[nt][q] + bj, 0.f);
                if (OUT_BF16) ((ushort_t*)outv)[orow * NOUT + col] = f2bf(v);
                else          ((float*)outv)[orow * NOUT + col] = v;
            }
        }
    }
}

// ---------------- MFMA GEMM (K=128): out = [relu]( A @ packedW [+ Cpre] [+ b] ) ----------------
// OUTMODE: 0 = f32 row-major, 1 = bf16 row-major, 2 = fp8 row-major
template<int NOUT, int OUTMODE, bool PRELOAD, bool HASBIAS, bool RELU>
__global__ __launch_bounds__(256) void mfma_gemm_k128_kernel(
        const ushort_t* __restrict__ A, const ushort_t* __restrict__ pack,
        const float* __restrict__ bias, const ushort_t* __restrict__ Cpre,
        void* __restrict__ outv) {
    constexpr int NT = NOUT / 16;
    int lane = threadIdx.x & 63;
    int wave = threadIdx.x >> 6;
    long m0 = (long)blockIdx.x * 64 + wave * 16;
    int r = lane & 15;
    int quad = lane >> 4;
    long arow = m0 + r;
    if (arow > N_NODES - 1) arow = N_NODES - 1;

    bf16x8 areg[4];
    #pragma unroll
    for (int kt = 0; kt < 4; ++kt)
        areg[kt] = *(const bf16x8*)(A + arow * 128 + kt * 32 + quad * 8);

    f32x4 acc[NT];
    #pragma unroll
    for (int nt = 0; nt < NT; ++nt) {
        if (PRELOAD) {
            int col = nt * 16 + r;
            #pragma unroll
            for (int q = 0; q < 4; ++q) {
                long row = m0 + quad * 4 + q;
                if (row > N_NODES - 1) row = N_NODES - 1;
                acc[nt][q] = bf2f(Cpre[row * NOUT + col]);
            }
        } else {
            acc[nt] = (f32x4){0.f, 0.f, 0.f, 0.f};
        }
    }

    #pragma unroll
    for (int nt = 0; nt < NT; ++nt) {
        #pragma unroll
        for (int kt = 0; kt < 4; ++kt) {
            bf16x8 bfrag = *(const bf16x8*)(pack + ((long)(nt * 4 + kt) * 64 + lane) * 8);
            acc[nt] = __builtin_amdgcn_mfma_f32_16x16x32_bf16(areg[kt], bfrag, acc[nt], 0, 0, 0);
        }
    }

    #pragma unroll
    for (int nt = 0; nt < NT; ++nt) {
        int col = nt * 16 + r;
        float bj = HASBIAS ? bias[col] : 0.f;
        #pragma unroll
        for (int q = 0; q < 4; ++q) {
            long orow = m0 + quad * 4 + q;
            if (orow < N_NODES) {
                float v = acc[nt][q] + bj;
                if (RELU) v = fmaxf(v, 0.f);
                if (OUTMODE == 2)      ((uchar_t*)outv)[orow * NOUT + col] = f2fp8_byte(v);
                else if (OUTMODE == 1) ((ushort_t*)outv)[orow * NOUT + col] = f2bf(v);
                else                   ((float*)outv)[orow * NOUT + col] = v;
            }
        }
    }
}

extern "C" void kernel_launch(void* const* d_in, const int* in_sizes, int n_in,
                              void* d_out, int out_size, void* d_ws, size_t ws_size,
                              hipStream_t stream) {
    const float* x    = (const float*)d_in[0];
    const int*   ei   = (const int*)d_in[1];
    const float* W1_l = (const float*)d_in[2];
    const float* W1_r = (const float*)d_in[3];
    const float* b1   = (const float*)d_in[4];
    const float* W2_l = (const float*)d_in[5];
    const float* W2_r = (const float*)d_in[6];
    const float* b2   = (const float*)d_in[7];
    float* out = (float*)d_out;

    const int* src = ei;
    const int* dst = ei + N_EDGES;

    // workspace layout (16B aligned). g8/meang alias mean1; x8 aliases hb
    // (x8 dead before mfma_mlp writes hb; mean1 dead before gemm writes g8).
    int*  gCur   = (int*)d_ws;                        // 512
    int2* off2   = (int2*)(gCur + 512);               // 100608 int2
    int*  bedges = (int*)(off2 + 100608);             // NB*CAP
    int*  csr    = bedges + NB * CAP;                 // NB*CAP
    ushort_t* xb    = (ushort_t*)(csr + NB * CAP);    // 25.6 MB row-major [N][128] bf16
    ushort_t* mean1 = xb + (long)N_NODES * 128;       // 25.6 MB region
    uchar_t*  g8    = (uchar_t*)mean1;                // alias: 6.4 MB fp8 [N][64]
    ushort_t* meang = mean1 + (long)N_NODES * 64;     // alias upper half: bf16 [N][64]
    ushort_t* hb    = mean1 + (long)N_NODES * 128;    // 25.6 MB row-major [N][128] bf16
    uchar_t*  x8    = (uchar_t*)hb;                   // alias: 12.8 MB fp8 [N][128]
    ushort_t* pack1  = hb + (long)N_NODES * 128;      // 256*128 bf16
    ushort_t* pack2l = pack1 + 256 * 128;             // 128*64
    ushort_t* pack2r = pack2l + 128 * 64;             // 128*64

    // ---- fused prep: weight packs + cursor init (1 launch) ----
    prep_kernel<<<26, 256, 0, stream>>>(W1_l, W1_r, pack1, W2_l, pack2l, W2_r, pack2r, gCur);

    // ---- CSR build (fixed-stride buckets) ----
    bucket_scatter_kernel<<<PART_BLOCKS, 256, 0, stream>>>(src, dst, gCur, bedges);
    bucket_sort_kernel<<<NB, 256, 0, stream>>>(gCur, bedges, csr, off2);

    // ---- precision prep (single pass over x) ----
    cvt_both_kernel<<<((long)N_NODES * 128 / 16 + 255) / 256, 256, 0, stream>>>(
        x, xb, x8, (long)N_NODES * 128);

    // ---- layer 1: mean1 = gather(x_fp8); h = relu([mean1|x]@W1 + b1) ----
    gather_mean_fp8_kernel<<<(N_NODES + 31) / 32, 256, 0, stream>>>(off2, csr, x8, mean1);
    mfma_mlp_kernel<128, true><<<(N_NODES + 63) / 64, 256, 0, stream>>>(mean1, xb, pack1, b1, hb);

    // ---- layer 2: g8 = fp8(h@W2_l); meang = gather(g8); out = relu(meang + h@W2_r + b2) ----
    mfma_gemm_k128_kernel<64, 2, false, false, false><<<(N_NODES + 63) / 64, 256, 0, stream>>>(
        hb, pack2l, nullptr, nullptr, g8);
    gather_mean64_fp8_kernel<<<(N_NODES + 63) / 64, 256, 0, stream>>>(off2, csr, g8, meang);
    mfma_gemm_k128_kernel<64, 0, true, true, true><<<(N_NODES + 63) / 64, 256, 0, stream>>>(
        hb, pack2r, b2, meang, out);
}

// Round 14
// 245.953 us; speedup vs baseline: 1.1655x; 1.0676x over previous
//
#include <hip/hip_runtime.h>

#define N_NODES 100000
#define N_EDGES 1600000
#define D_IN 128
#define D_HID 128
#define D_LAT 64

#define BSHIFT 8                          // 256 nodes per bucket
#define NB 392                            // ceil(100352 / 256) buckets
#define CAP 4608                          // slots per bucket region (mean 4082 + 8.2 sigma)
#define EPB 4096                          // edges per partition block
#define PART_BLOCKS ((N_EDGES + EPB - 1) / EPB)   // 391
#define CVT_BLOCKS (((long)N_NODES * 128 / 16 + 255) / 256)   // 3125

typedef unsigned short ushort_t;
typedef unsigned int uint_t;
typedef unsigned char uchar_t;
using bf16x8 = __attribute__((ext_vector_type(8))) short;
using f32x4  = __attribute__((ext_vector_type(4))) float;
using f32x2  = __attribute__((ext_vector_type(2))) float;

__device__ inline ushort_t f2bf(float f) {
    uint_t u = __float_as_uint(f);
    return (ushort_t)((u + 0x7fffu + ((u >> 16) & 1u)) >> 16);   // RNE
}
__device__ inline uint_t pack2bf(float a, float b) {
    return (uint_t)f2bf(a) | ((uint_t)f2bf(b) << 16);
}
__device__ inline float bf2f(ushort_t u) {
    return __uint_as_float(((uint_t)u) << 16);
}

// ---------------- fp8 e4m3 helpers (word-select must be compile-time) ----------------
#if __has_builtin(__builtin_amdgcn_cvt_pk_f32_fp8) && __has_builtin(__builtin_amdgcn_cvt_pk_fp8_f32)
#define HW_FP8 1
template<bool HI>
__device__ inline f32x2 fp8pk2f(uint_t v) {
    return __builtin_amdgcn_cvt_pk_f32_fp8(v, HI);       // HI is an ICE here
}
__device__ inline uint_t f2fp8pk4(float a, float b, float c, float d) {
    uint_t w = __builtin_amdgcn_cvt_pk_fp8_f32(a, b, 0, false);
    w = __builtin_amdgcn_cvt_pk_fp8_f32(c, d, w, true);
    return w;
}
__device__ inline uchar_t f2fp8_byte(float f) {
    return (uchar_t)(__builtin_amdgcn_cvt_pk_fp8_f32(f, f, 0, false) & 0xff);
}
#else
// fallback: software e4m3fn (normals exact w/ RNE; subnormals flushed)
__device__ inline float fp8b2f(uint_t b) {
    uint_t em = b & 0x7f;
    if (em == 0) return 0.f;
    uint_t bits = ((em << 20) + (120u << 23)) | ((b & 0x80u) << 24);
    return __uint_as_float(bits);
}
template<bool HI>
__device__ inline f32x2 fp8pk2f(uint_t v) {
    uint_t w = HI ? (v >> 16) : v;
    f32x2 r; r.x = fp8b2f(w & 0xff); r.y = fp8b2f((w >> 8) & 0xff);
    return r;
}
__device__ inline uint_t f2fp8_1(float f) {
    uint_t u = __float_as_uint(f);
    uint_t s = (u >> 31) << 7;
    uint_t au = u & 0x7fffffff;
    if (au >= 0x43e00000u) return s | 0x7e;              // clamp to 448
    if (au < 0x3c000000u) return s;                      // < 2^-7 -> 0 (approx)
    uint_t r = au + 0x0007ffffu + ((au >> 20) & 1u);     // RNE at 3 mantissa bits
    return s | (((r >> 20) - (120u << 3)) & 0x7f);
}
__device__ inline uint_t f2fp8pk4(float a, float b, float c, float d) {
    return f2fp8_1(a) | (f2fp8_1(b) << 8) | (f2fp8_1(c) << 16) | (f2fp8_1(d) << 24);
}
__device__ inline uchar_t f2fp8_byte(float f) { return (uchar_t)f2fp8_1(f); }
#endif

__device__ inline void accf8x4(float* a, uint_t w, int base) {
    f32x2 p0 = fp8pk2f<false>(w);
    f32x2 p1 = fp8pk2f<true>(w);
    a[base + 0] += p0.x; a[base + 1] += p0.y;
    a[base + 2] += p1.x; a[base + 3] += p1.y;
}
__device__ inline void accf8x16(float* a, uint4 u) {
    accf8x4(a, u.x, 0); accf8x4(a, u.y, 4); accf8x4(a, u.z, 8); accf8x4(a, u.w, 12);
}

// ---------------- fused prep: weight packs + cursor init + x conversion ----------------
// blocks 0..15: pack1; 16..19: pack2l; 20..23: pack2r; 24..25: gCur; 26..: cvt x
__device__ inline void pack_w256(const float* Wl, const float* Wr, ushort_t* pack,
                                 int N, int tid) {
    int lane = tid & 63;
    int t = tid >> 6;
    int kt = t & 7;
    int nt = t >> 3;
    int n = nt * 16 + (lane & 15);
    int kbase = kt * 32 + (lane >> 4) * 8;
    ushort_t v[8];
    #pragma unroll
    for (int j = 0; j < 8; ++j) {
        int k = kbase + j;
        float w = (k < 128) ? Wl[k * N + n] : Wr[(k - 128) * N + n];
        v[j] = f2bf(w);
    }
    *(uint4*)(pack + (long)tid * 8) = *(uint4*)v;
}
__device__ inline void pack_w128(const float* W, ushort_t* pack, int N, int tid) {
    int lane = tid & 63;
    int t = tid >> 6;
    int kt = t & 3;
    int nt = t >> 2;
    int n = nt * 16 + (lane & 15);
    int kbase = kt * 32 + (lane >> 4) * 8;
    ushort_t v[8];
    #pragma unroll
    for (int j = 0; j < 8; ++j) v[j] = f2bf(W[(kbase + j) * N + n]);
    *(uint4*)(pack + (long)tid * 8) = *(uint4*)v;
}

__global__ __launch_bounds__(256) void prep_kernel(
        const float* __restrict__ W1_l, const float* __restrict__ W1_r,
        ushort_t* __restrict__ pack1,
        const float* __restrict__ W2_l, ushort_t* __restrict__ pack2l,
        const float* __restrict__ W2_r, ushort_t* __restrict__ pack2r,
        int* __restrict__ gCur,
        const float* __restrict__ x, ushort_t* __restrict__ xb,
        uchar_t* __restrict__ x8) {
    int b = blockIdx.x;
    if (b < 16) {
        pack_w256(W1_l, W1_r, pack1, 128, b * 256 + threadIdx.x);
    } else if (b < 20) {
        pack_w128(W2_l, pack2l, 64, (b - 16) * 256 + threadIdx.x);
    } else if (b < 24) {
        pack_w128(W2_r, pack2r, 64, (b - 20) * 256 + threadIdx.x);
    } else if (b < 26) {
        int t = (b - 24) * 256 + threadIdx.x;
        if (t < NB) gCur[t] = t * CAP;
    } else {
        long i = ((long)(b - 26) * 256 + threadIdx.x) * 16;
        if (i >= (long)N_NODES * 128) return;
        float4 a = *(const float4*)(x + i);
        float4 bb = *(const float4*)(x + i + 4);
        float4 c = *(const float4*)(x + i + 8);
        float4 d = *(const float4*)(x + i + 12);
        uint4 ob0, ob1;
        ob0.x = pack2bf(a.x, a.y);  ob0.y = pack2bf(a.z, a.w);
        ob0.z = pack2bf(bb.x, bb.y); ob0.w = pack2bf(bb.z, bb.w);
        ob1.x = pack2bf(c.x, c.y);  ob1.y = pack2bf(c.z, c.w);
        ob1.z = pack2bf(d.x, d.y);  ob1.w = pack2bf(d.z, d.w);
        *(uint4*)(xb + i) = ob0;
        *(uint4*)(xb + i + 8) = ob1;
        uint4 o8;
        o8.x = f2fp8pk4(a.x, a.y, a.z, a.w);
        o8.y = f2fp8pk4(bb.x, bb.y, bb.z, bb.w);
        o8.z = f2fp8pk4(c.x, c.y, c.z, c.w);
        o8.w = f2fp8pk4(d.x, d.y, d.z, d.w);
        *(uint4*)(x8 + i) = o8;
    }
}

// ---------------- CSR build: fixed-stride bucketed counting sort ----------------
__global__ __launch_bounds__(256) void bucket_scatter_kernel(const int* __restrict__ src,
                                                             const int* __restrict__ dst,
                                                             int* __restrict__ gCur,
                                                             int* __restrict__ bedges) {
    __shared__ int h[NB];
    __shared__ int start[NB];
    for (int j = threadIdx.x; j < NB; j += 256) h[j] = 0;
    __syncthreads();
    long base = (long)blockIdx.x * EPB + threadIdx.x * 16;   // 16 consecutive edges/thread
    int dc[16], sc[16];
    int cnt = 0;
    if (base + 16 <= N_EDGES) {
        #pragma unroll
        for (int j = 0; j < 4; ++j) {
            int4 d4 = *(const int4*)(dst + base + j * 4);
            int4 s4 = *(const int4*)(src + base + j * 4);
            dc[j * 4 + 0] = d4.x; dc[j * 4 + 1] = d4.y; dc[j * 4 + 2] = d4.z; dc[j * 4 + 3] = d4.w;
            sc[j * 4 + 0] = s4.x; sc[j * 4 + 1] = s4.y; sc[j * 4 + 2] = s4.z; sc[j * 4 + 3] = s4.w;
        }
        cnt = 16;
    } else if (base < N_EDGES) {
        cnt = (int)(N_EDGES - base);
        for (int j = 0; j < cnt; ++j) { dc[j] = dst[base + j]; sc[j] = src[base + j]; }
    }
    for (int j = 0; j < cnt; ++j) atomicAdd(&h[dc[j] >> BSHIFT], 1);
    __syncthreads();
    for (int j = threadIdx.x; j < NB; j += 256)
        start[j] = h[j] ? atomicAdd(&gCur[j], h[j]) : 0;
    __syncthreads();
    for (int j = 0; j < cnt; ++j) {
        int b = dc[j] >> BSHIFT;
        int p = atomicAdd(&start[b], 1);
        if (p < (b + 1) * CAP)                     // overflow clamp (P ~ 1e-16)
            bedges[p] = ((dc[j] & 255) << 24) | sc[j];
    }
}

// per-bucket LDS counting sort; int4 reads (CAP region is 16B-aligned + padded)
__global__ __launch_bounds__(256) void bucket_sort_kernel(const int* __restrict__ gCur,
                                                          const int* __restrict__ bedges,
                                                          int* __restrict__ csr,
                                                          int2* __restrict__ off2) {
    __shared__ int sdata[256];
    __shared__ int cur[256];
    int b = blockIdx.x, t = threadIdx.x;
    int r0 = b * CAP;
    int n = gCur[b] - r0;
    if (n > CAP) n = CAP;
    cur[t] = 0;
    __syncthreads();
    for (int k = t * 4; k < n; k += 1024) {
        int4 v4 = *(const int4*)(bedges + r0 + k);
        int m = n - k;
        atomicAdd(&cur[(unsigned)v4.x >> 24], 1);
        if (m > 1) atomicAdd(&cur[(unsigned)v4.y >> 24], 1);
        if (m > 2) atomicAdd(&cur[(unsigned)v4.z >> 24], 1);
        if (m > 3) atomicAdd(&cur[(unsigned)v4.w >> 24], 1);
    }
    __syncthreads();
    int c = cur[t];
    sdata[t] = c;
    __syncthreads();
    for (int d = 1; d < 256; d <<= 1) {
        int u = (t >= d) ? sdata[t - d] : 0;
        __syncthreads();
        sdata[t] += u;
        __syncthreads();
    }
    int ex = (t == 0) ? 0 : sdata[t - 1];
    off2[(b << BSHIFT) + t] = make_int2(r0 + ex, c);
    cur[t] = ex;
    __syncthreads();
    for (int k = t * 4; k < n; k += 1024) {
        int4 v4 = *(const int4*)(bedges + r0 + k);
        int m = n - k;
        {
            int p = atomicAdd(&cur[(unsigned)v4.x >> 24], 1);
            csr[r0 + p] = v4.x & 0xFFFFFF;
        }
        if (m > 1) {
            int p = atomicAdd(&cur[(unsigned)v4.y >> 24], 1);
            csr[r0 + p] = v4.y & 0xFFFFFF;
        }
        if (m > 2) {
            int p = atomicAdd(&cur[(unsigned)v4.z >> 24], 1);
            csr[r0 + p] = v4.z & 0xFFFFFF;
        }
        if (m > 3) {
            int p = atomicAdd(&cur[(unsigned)v4.w >> 24], 1);
            csr[r0 + p] = v4.w & 0xFFFFFF;
        }
    }
}

// ---------------- gather-mean 128-dim fp8, 4-edge pipeline ----------------
// 8 lanes per node (16 dims / 16 B each), 32 nodes per 256-thread block.
__global__ __launch_bounds__(256) void gather_mean_fp8_kernel(
        const int2* __restrict__ off2, const int* __restrict__ csr_src,
        const uchar_t* __restrict__ x8, ushort_t* __restrict__ mean_out) {
    int lane  = threadIdx.x & 7;
    int local = threadIdx.x >> 3;
    long i = (long)blockIdx.x * 32 + local;
    if (i >= N_NODES) return;
    int2 bd = off2[i];
    int beg = bd.x, n = bd.y;
    const uchar_t* base = x8 + lane * 16;
    float acc[16];
    #pragma unroll
    for (int j = 0; j < 16; ++j) acc[j] = 0.f;
    int k = 0;
    for (; k + 4 <= n; k += 4) {
        int s0 = csr_src[beg + k];
        int s1 = csr_src[beg + k + 1];
        int s2 = csr_src[beg + k + 2];
        int s3 = csr_src[beg + k + 3];
        uint4 u0 = *(const uint4*)(base + (long)s0 * 128);
        uint4 u1 = *(const uint4*)(base + (long)s1 * 128);
        uint4 u2 = *(const uint4*)(base + (long)s2 * 128);
        uint4 u3 = *(const uint4*)(base + (long)s3 * 128);
        accf8x16(acc, u0); accf8x16(acc, u1); accf8x16(acc, u2); accf8x16(acc, u3);
    }
    for (; k < n; ++k) {
        int s0 = csr_src[beg + k];
        uint4 u0 = *(const uint4*)(base + (long)s0 * 128);
        accf8x16(acc, u0);
    }
    float inv = (n > 0) ? 1.f / (float)n : 0.f;
    uint4 o0, o1;
    o0.x = pack2bf(acc[0] * inv,  acc[1] * inv);
    o0.y = pack2bf(acc[2] * inv,  acc[3] * inv);
    o0.z = pack2bf(acc[4] * inv,  acc[5] * inv);
    o0.w = pack2bf(acc[6] * inv,  acc[7] * inv);
    o1.x = pack2bf(acc[8] * inv,  acc[9] * inv);
    o1.y = pack2bf(acc[10] * inv, acc[11] * inv);
    o1.z = pack2bf(acc[12] * inv, acc[13] * inv);
    o1.w = pack2bf(acc[14] * inv, acc[15] * inv);
    ushort_t* mp = mean_out + i * 128 + lane * 16;
    *(uint4*)mp = o0;
    *(uint4*)(mp + 8) = o1;
}

// ---------------- fused MLP1 + g-pretransform ----------------
// h = relu([mean|x]@W1 + b1) -> hb (bf16); then per-wave LDS transpose of the
// h tile and g8 = fp8(h@W2_l) without re-reading hb from global.
#define HSTRIDE 132   // 16-row x 128-col bf16 tile, +4 pad breaks 256B bank stride
__global__ __launch_bounds__(256) void mfma_mlp_fused_kernel(
        const ushort_t* __restrict__ Am, const ushort_t* __restrict__ Ax,
        const ushort_t* __restrict__ pack1, const float* __restrict__ bias,
        const ushort_t* __restrict__ pack2l,
        ushort_t* __restrict__ hb, uchar_t* __restrict__ g8) {
    __shared__ ushort_t htile[4][16 * HSTRIDE];
    int lane = threadIdx.x & 63;
    int wave = threadIdx.x >> 6;
    long m0 = (long)blockIdx.x * 64 + wave * 16;
    int r = lane & 15;
    int quad = lane >> 4;
    long arow = m0 + r;
    if (arow > N_NODES - 1) arow = N_NODES - 1;

    bf16x8 areg[8];
    #pragma unroll
    for (int kt = 0; kt < 8; ++kt) {
        const ushort_t* s = (kt < 4) ? Am : Ax;
        int k = (kt & 3) * 32 + quad * 8;
        areg[kt] = *(const bf16x8*)(s + arow * 128 + k);
    }

    f32x4 acc[8];
    #pragma unroll
    for (int nt = 0; nt < 8; ++nt) acc[nt] = (f32x4){0.f, 0.f, 0.f, 0.f};
    #pragma unroll
    for (int nt = 0; nt < 8; ++nt) {
        #pragma unroll
        for (int kt = 0; kt < 8; ++kt) {
            bf16x8 bfrag = *(const bf16x8*)(pack1 + ((long)(nt * 8 + kt) * 64 + lane) * 8);
            acc[nt] = __builtin_amdgcn_mfma_f32_16x16x32_bf16(areg[kt], bfrag, acc[nt], 0, 0, 0);
        }
    }

    // epilogue: h -> global + per-wave LDS tile (row = quad*4+q, col = nt*16+r)
    #pragma unroll
    for (int nt = 0; nt < 8; ++nt) {
        int col = nt * 16 + r;
        float bj = bias[col];
        #pragma unroll
        for (int q = 0; q < 4; ++q) {
            long orow = m0 + quad * 4 + q;
            float v = fmaxf(acc[nt][q] + bj, 0.f);
            ushort_t hv = f2bf(v);
            if (orow < N_NODES) hb[orow * 128 + col] = hv;
            htile[wave][(quad * 4 + q) * HSTRIDE + col] = hv;
        }
    }
    // wave-local dependency only: no __syncthreads needed.
    // stage 2: g = h @ W2_l (K=128 -> 64), A-frags from LDS tile
    bf16x8 areg2[4];
    #pragma unroll
    for (int kt = 0; kt < 4; ++kt)
        areg2[kt] = *(const bf16x8*)(&htile[wave][r * HSTRIDE + kt * 32 + quad * 8]);
    f32x4 gacc[4];
    #pragma unroll
    for (int nt = 0; nt < 4; ++nt) gacc[nt] = (f32x4){0.f, 0.f, 0.f, 0.f};
    #pragma unroll
    for (int nt = 0; nt < 4; ++nt) {
        #pragma unroll
        for (int kt = 0; kt < 4; ++kt) {
            bf16x8 bfrag = *(const bf16x8*)(pack2l + ((long)(nt * 4 + kt) * 64 + lane) * 8);
            gacc[nt] = __builtin_amdgcn_mfma_f32_16x16x32_bf16(areg2[kt], bfrag, gacc[nt], 0, 0, 0);
        }
    }
    #pragma unroll
    for (int nt = 0; nt < 4; ++nt) {
        int col = nt * 16 + r;
        #pragma unroll
        for (int q = 0; q < 4; ++q) {
            long orow = m0 + quad * 4 + q;
            if (orow < N_NODES) g8[orow * 64 + col] = f2fp8_byte(gacc[nt][q]);
        }
    }
}

// ---------------- fused final: gather(g8) prologue + out = relu(mean + h@W2_r + b2) ----
#define MSTRIDE 68    // 64-row x 64-col bf16 mean tile, padded
__global__ __launch_bounds__(256) void mfma_final_kernel(
        const int2* __restrict__ off2, const int* __restrict__ csr_src,
        const uchar_t* __restrict__ g8,
        const ushort_t* __restrict__ hb, const ushort_t* __restrict__ pack2r,
        const float* __restrict__ b2, float* __restrict__ out) {
    __shared__ ushort_t mtile[64 * MSTRIDE];
    long m0 = (long)blockIdx.x * 64;
    // --- prologue: gather mean for this block's 64 rows into LDS ---
    {
        int lane  = threadIdx.x & 3;          // 16 dims (16 B) per lane
        int local = threadIdx.x >> 2;         // node within block
        long i = m0 + local;
        if (i > N_NODES - 1) i = N_NODES - 1; // off2 valid through 100351
        int2 bd = off2[i];
        int beg = bd.x, n = bd.y;
        const uchar_t* base = g8 + lane * 16;
        float acc[16];
        #pragma unroll
        for (int j = 0; j < 16; ++j) acc[j] = 0.f;
        int k = 0;
        for (; k + 4 <= n; k += 4) {
            int s0 = csr_src[beg + k];
            int s1 = csr_src[beg + k + 1];
            int s2 = csr_src[beg + k + 2];
            int s3 = csr_src[beg + k + 3];
            uint4 u0 = *(const uint4*)(base + (long)s0 * 64);
            uint4 u1 = *(const uint4*)(base + (long)s1 * 64);
            uint4 u2 = *(const uint4*)(base + (long)s2 * 64);
            uint4 u3 = *(const uint4*)(base + (long)s3 * 64);
            accf8x16(acc, u0); accf8x16(acc, u1); accf8x16(acc, u2); accf8x16(acc, u3);
        }
        for (; k < n; ++k) {
            int s0 = csr_src[beg + k];
            uint4 u0 = *(const uint4*)(base + (long)s0 * 64);
            accf8x16(acc, u0);
        }
        float inv = (n > 0) ? 1.f / (float)n : 0.f;
        uint4 o0, o1;
        o0.x = pack2bf(acc[0] * inv,  acc[1] * inv);
        o0.y = pack2bf(acc[2] * inv,  acc[3] * inv);
        o0.z = pack2bf(acc[4] * inv,  acc[5] * inv);
        o0.w = pack2bf(acc[6] * inv,  acc[7] * inv);
        o1.x = pack2bf(acc[8] * inv,  acc[9] * inv);
        o1.y = pack2bf(acc[10] * inv, acc[11] * inv);
        o1.z = pack2bf(acc[12] * inv, acc[13] * inv);
        o1.w = pack2bf(acc[14] * inv, acc[15] * inv);
        ushort_t* mp = mtile + local * MSTRIDE + lane * 16;
        *(uint4*)mp = o0;
        *(uint4*)(mp + 8) = o1;
    }
    __syncthreads();
    // --- GEMM: out = relu(mean + h@W2_r + b2) ---
    int lane = threadIdx.x & 63;
    int wave = threadIdx.x >> 6;
    long mw = m0 + wave * 16;
    int r = lane & 15;
    int quad = lane >> 4;
    long arow = mw + r;
    if (arow > N_NODES - 1) arow = N_NODES - 1;

    bf16x8 areg[4];
    #pragma unroll
    for (int kt = 0; kt < 4; ++kt)
        areg[kt] = *(const bf16x8*)(hb + arow * 128 + kt * 32 + quad * 8);

    f32x4 acc[4];
    #pragma unroll
    for (int nt = 0; nt < 4; ++nt) {
        int col = nt * 16 + r;
        #pragma unroll
        for (int q = 0; q < 4; ++q) {
            int rowl = wave * 16 + quad * 4 + q;
            acc[nt][q] = bf2f(mtile[rowl * MSTRIDE + col]);
        }
    }
    #pragma unroll
    for (int nt = 0; nt < 4; ++nt) {
        #pragma unroll
        for (int kt = 0; kt < 4; ++kt) {
            bf16x8 bfrag = *(const bf16x8*)(pack2r + ((long)(nt * 4 + kt) * 64 + lane) * 8);
            acc[nt] = __builtin_amdgcn_mfma_f32_16x16x32_bf16(areg[kt], bfrag, acc[nt], 0, 0, 0);
        }
    }
    #pragma unroll
    for (int nt = 0; nt < 4; ++nt) {
        int col = nt * 16 + r;
        float bj = b2[col];
        #pragma unroll
        for (int q = 0; q < 4; ++q) {
            long orow = mw + quad * 4 + q;
            if (orow < N_NODES)
                out[orow * 64 + col] = fmaxf(acc[nt][q] + bj, 0.f);
        }
    }
}

extern "C" void kernel_launch(void* const* d_in, const int* in_sizes, int n_in,
                              void* d_out, int out_size, void* d_ws, size_t ws_size,
                              hipStream_t stream) {
    const float* x    = (const float*)d_in[0];
    const int*   ei   = (const int*)d_in[1];
    const float* W1_l = (const float*)d_in[2];
    const float* W1_r = (const float*)d_in[3];
    const float* b1   = (const float*)d_in[4];
    const float* W2_l = (const float*)d_in[5];
    const float* W2_r = (const float*)d_in[6];
    const float* b2   = (const float*)d_in[7];
    float* out = (float*)d_out;

    const int* src = ei;
    const int* dst = ei + N_EDGES;

    // workspace layout (16B aligned). x8 aliases hb (x8 dead before mlp writes hb).
    // g8 has its OWN region now (fused mlp writes g8 while other blocks still read mean1).
    int*  gCur   = (int*)d_ws;                        // 512
    int2* off2   = (int2*)(gCur + 512);               // 100608 int2
    int*  bedges = (int*)(off2 + 100608);             // NB*CAP
    int*  csr    = bedges + NB * CAP;                 // NB*CAP
    ushort_t* xb    = (ushort_t*)(csr + NB * CAP);    // 25.6 MB row-major [N][128] bf16
    ushort_t* mean1 = xb + (long)N_NODES * 128;       // 25.6 MB bf16 [N][128]
    ushort_t* hb    = mean1 + (long)N_NODES * 128;    // 25.6 MB bf16 [N][128]
    uchar_t*  x8    = (uchar_t*)hb;                   // alias: 12.8 MB fp8 [N][128]
    ushort_t* pack1  = hb + (long)N_NODES * 128;      // 256*128 bf16
    ushort_t* pack2l = pack1 + 256 * 128;             // 128*64
    ushort_t* pack2r = pack2l + 128 * 64;             // 128*64
    uchar_t*  g8     = (uchar_t*)(pack2r + 128 * 64); // 6.4 MB fp8 [N][64]

    // ---- fused prep: weight packs + cursor init + x->bf16/fp8 (1 launch) ----
    prep_kernel<<<26 + CVT_BLOCKS, 256, 0, stream>>>(
        W1_l, W1_r, pack1, W2_l, pack2l, W2_r, pack2r, gCur, x, xb, x8);

    // ---- CSR build (fixed-stride buckets) ----
    bucket_scatter_kernel<<<PART_BLOCKS, 256, 0, stream>>>(src, dst, gCur, bedges);
    bucket_sort_kernel<<<NB, 256, 0, stream>>>(gCur, bedges, csr, off2);

    // ---- layer 1 (+ fused g pretransform): mean1 = gather(x8);
    //      h = relu([mean1|x]@W1+b1); g8 = fp8(h@W2_l) ----
    gather_mean_fp8_kernel<<<(N_NODES + 31) / 32, 256, 0, stream>>>(off2, csr, x8, mean1);
    mfma_mlp_fused_kernel<<<(N_NODES + 63) / 64, 256, 0, stream>>>(
        mean1, xb, pack1, b1, pack2l, hb, g8);

    // ---- layer 2 (fully fused): out = relu(gather(g8) + h@W2_r + b2) ----
    mfma_final_kernel<<<(N_NODES + 63) / 64, 256, 0, stream>>>(
        off2, csr, g8, hb, pack2r, b2, out);
}